// Round 2
// baseline (604.271 us; speedup 1.0000x reference)
//
#include <hip/hip_runtime.h>
#include <math.h>

#define HD   64
#define EIN  8
#define SAS  168          // sW1 row stride in u16 (336 B): bank step 20 -> conflict-light
#define W2S  72           // sW2/X1 row stride in u16 (144 B)
#define NORM_INV 0.01f
#define NTH  256          // 4 waves/block
#define NBLK 1024         // 4 blocks/CU x 256 CUs (LDS: 4 x 40960 B = exactly 160 KiB)
#define NWAVES (NBLK * (NTH / 64))

typedef short bf16x8 __attribute__((ext_vector_type(8)));
typedef float f32x4  __attribute__((ext_vector_type(4)));
typedef float f4v    __attribute__((ext_vector_type(4)));

__device__ __forceinline__ unsigned short f2bf(float f) {
    union { float f; unsigned u; } v; v.f = f;
    unsigned r = v.u + 0x7FFFu + ((v.u >> 16) & 1u);
    return (unsigned short)(r >> 16);
}
__device__ __forceinline__ unsigned pk2(float a, float b) {
    return (unsigned)f2bf(a) | ((unsigned)f2bf(b) << 16);
}
__device__ __forceinline__ float silu_f(float x) {
    return x * __builtin_amdgcn_rcpf(1.0f + __expf(-x));
}
__device__ __forceinline__ bf16x8 pack_f8(f4v a, f4v b) {
    union { bf16x8 v; uint4 u; } pk;
    pk.u.x = pk2(a.x, a.y); pk.u.y = pk2(a.z, a.w);
    pk.u.z = pk2(b.x, b.y); pk.u.w = pk2(b.z, b.w);
    return pk.v;
}

// prep: h -> bf16 table in ws + coord -> out copy
__global__ void prep_h_kernel(const float* __restrict__ h, unsigned short* __restrict__ hbf,
                              int npairs, const float* __restrict__ coord,
                              float* __restrict__ out, int n3) {
    int i = blockIdx.x * blockDim.x + threadIdx.x;
    if (i < npairs) {
        float2 v = reinterpret_cast<const float2*>(h)[i];
        ushort2 o; o.x = f2bf(v.x); o.y = f2bf(v.y);
        reinterpret_cast<ushort2*>(hbf)[i] = o;
    }
    if (i < n3) out[i] = coord[i];
}

__global__ void prep_out_kernel(const float* __restrict__ coord,
                                float* __restrict__ out, int n3) {
    int i = blockIdx.x * blockDim.x + threadIdx.x;
    if (i < n3) out[i] = coord[i];
}

// r7: r6 post-mortem -- the pipeline state (bf16x8 arrays written via lambda
// pointer) was demoted to scratch: VGPR 84->64, FETCH 0.8->1.7 GB (= 100K
// groups x 64 lanes x 160 B scratch round-trip). Same pipeline, but ALL
// pipeline state in NAMED registers (f0..f4 / n0..n4, macros not lambdas).
// Occupancy lever (4 blocks/CU, LDS = exactly 160 KiB) retained: it worked
// (34 -> 47%).

#define LOAD_IDX(G, EV, ROW, COL) do {                                  \
    EV = (G) * 16 + m;                                                  \
    int ec_ = (EV < E_) ? EV : (E_ - 1);                                \
    ROW = eidx[ec_];                                                    \
    COL = eidx[(size_t)E_ + ec_];                                       \
} while (0)

#define LOAD_FRAG(EV, ROW, COL, CR, CC, F0, F1, F2, F3, F4) do {        \
    CR = 0.f; CC = 0.f;                                                 \
    if (q < 3) { CR = coord[(ROW) * 3 + q]; CC = coord[(COL) * 3 + q]; }\
    if (HB) {                                                           \
        const bf16x8* hr_ = (const bf16x8*)(hbf + (size_t)(ROW) * HD);  \
        const bf16x8* hc_ = (const bf16x8*)(hbf + (size_t)(COL) * HD);  \
        F0 = hr_[q]; F1 = hr_[4 + q]; F2 = hc_[q]; F3 = hc_[4 + q];     \
    } else {                                                            \
        const f4v* hr_ = (const f4v*)(h + (size_t)(ROW) * HD);          \
        const f4v* hc_ = (const f4v*)(h + (size_t)(COL) * HD);          \
        F0 = pack_f8(hr_[q * 2],     hr_[q * 2 + 1]);                   \
        F1 = pack_f8(hr_[8 + q * 2], hr_[8 + q * 2 + 1]);               \
        F2 = pack_f8(hc_[q * 2],     hc_[q * 2 + 1]);                   \
        F3 = pack_f8(hc_[8 + q * 2], hc_[8 + q * 2 + 1]);               \
    }                                                                   \
    {                                                                   \
        int ec_ = ((EV) < E_) ? (EV) : (E_ - 1);                        \
        union { bf16x8 v; uint4 u; } pk_;                               \
        pk_.u.x = 0; pk_.u.y = 0; pk_.u.z = 0; pk_.u.w = 0;             \
        if (q == 0) {                                                   \
            f4v a0_ = ((const f4v*)(eattr + (size_t)ec_ * EIN))[0];     \
            f4v a1_ = ((const f4v*)(eattr + (size_t)ec_ * EIN))[1];     \
            pk_.u.x = pk2(a0_.x, a0_.y); pk_.u.y = pk2(a0_.z, a0_.w);   \
            pk_.u.z = pk2(a1_.x, a1_.y); pk_.u.w = pk2(a1_.z, a1_.w);   \
        }                                                               \
        F4 = pk_.v;                                                     \
    }                                                                   \
} while (0)

template <bool HB>
__global__ __launch_bounds__(NTH, 4) void egnn_mfma_kernel(
    const float* __restrict__ h,             // fp32 h (when !HB)
    const unsigned short* __restrict__ hbf,  // bf16 h table in ws (when HB)
    const float* __restrict__ coord,
    const int*   __restrict__ eidx,   // [2][E]
    const float* __restrict__ eattr,  // [E][8]
    const float* __restrict__ W1f,    // [136][64] fp32
    const float* __restrict__ W2f,    // [64][64] fp32
    const float* __restrict__ b1,
    const float* __restrict__ b2,
    const float* __restrict__ W3,
    float* __restrict__ out,
    int E_)
{
    __shared__ unsigned short sW1[64 * SAS];      // 21504 B
    __shared__ unsigned short sW2[64 * W2S];      //  9216 B
    __shared__ unsigned short sX1[64 * W2S];      //  9216 B (4 waves x 16 rows)
    __shared__ float sB1[64], sB2[64], sW3[64];   //   768 B

    const int t = threadIdx.x;

    // ---- weights -> LDS (once per block) ----
    for (int i = t; i < 136 * 64; i += NTH) {
        int k = i >> 6, n = i & 63;
        sW1[n * SAS + k] = f2bf(W1f[i]);
    }
    for (int i = t; i < 24 * 64; i += NTH) {      // zero-pad W1 k=136..159
        int n = i / 24, k = 136 + (i - n * 24);
        sW1[n * SAS + k] = 0;
    }
    for (int i = t; i < 64 * 64; i += NTH) {
        int k = i >> 6, n = i & 63;
        sW2[n * W2S + k] = f2bf(W2f[i]);
    }
    if (t < 64) sB1[t] = b1[t];
    else if (t < 128) sB2[t - 64] = b2[t - 64];
    else if (t < 192) sW3[t - 128] = W3[t - 128];
    __syncthreads();                               // the ONLY barrier

    const int w = t >> 6, lane = t & 63;
    const int m = lane & 15, q = lane >> 4;

    unsigned short* x1Row = sX1 + (16 * w + m) * W2S;  // this lane's edge row

    const int ngroups = (E_ + 15) >> 4;
    const int g0 = blockIdx.x * (NTH / 64) + w;

    // ---- pipeline state: ALL named registers ----
    int   e_c = 0, row_c = 0, col_c = 0;
    float cr_c = 0.f, cc_c = 0.f;
    bf16x8 f0 = {}, f1 = {}, f2 = {}, f3 = {}, f4 = {};
    int   e_n = 0, row_n = 0, col_n = 0;

    // ---- prologue: fill the pipeline ----
    if (g0 < ngroups) {
        LOAD_IDX(g0, e_c, row_c, col_c);
        LOAD_FRAG(e_c, row_c, col_c, cr_c, cc_c, f0, f1, f2, f3, f4);
        if (g0 + NWAVES < ngroups)
            LOAD_IDX(g0 + NWAVES, e_n, row_n, col_n);
    }

    for (int g = g0; g < ngroups; g += NWAVES) {
        const int gn = g + NWAVES;

        // -------- prefetch next group's gathers BEFORE compute --------
        float cr_n = 0.f, cc_n = 0.f;
        bf16x8 n0 = f0, n1 = f1, n2 = f2, n3 = f3, n4 = f4;
        if (gn < ngroups)
            LOAD_FRAG(e_n, row_n, col_n, cr_n, cc_n, n0, n1, n2, n3, n4);
        int e_n2 = 0, row_n2 = 0, col_n2 = 0;
        if (gn + NWAVES < ngroups)
            LOAD_IDX(gn + NWAVES, e_n2, row_n2, col_n2);

        // ---------- layer 1: D1[n2][e] = sum_k W1[n2][k] * inp[e][k] ----------
        f32x4 acc1[4] = {};
#define L1STEP(S, F)                                                          \
        _Pragma("unroll")                                                     \
        for (int nt = 0; nt < 4; ++nt) {                                      \
            bf16x8 afrag = *(const bf16x8*)(sW1 + (16 * nt + m) * SAS + (S) * 32 + q * 8); \
            acc1[nt] = __builtin_amdgcn_mfma_f32_16x16x32_bf16(afrag, F, acc1[nt], 0, 0, 0); \
        }
        L1STEP(0, f0)
        L1STEP(1, f1)
        L1STEP(2, f2)
        L1STEP(3, f3)
        L1STEP(4, f4)
#undef L1STEP

        // silu(+b1) -> X1[e][k] packed b64 per lane
#pragma unroll
        for (int nt = 0; nt < 4; ++nt) {
            float4 bb = *(const float4*)(&sB1[16 * nt + 4 * q]);
            ushort4 o;
            o.x = f2bf(silu_f(acc1[nt][0] + bb.x));
            o.y = f2bf(silu_f(acc1[nt][1] + bb.y));
            o.z = f2bf(silu_f(acc1[nt][2] + bb.z));
            o.w = f2bf(silu_f(acc1[nt][3] + bb.w));
            *((ushort4*)(x1Row + 16 * nt + 4 * q)) = o;
        }

        // ---------- layer 2: D2[n2][e] = sum_k W2[n2][k] * X1[e][k] ----------
        f32x4 acc2[4] = {};
#pragma unroll
        for (int s = 0; s < 2; ++s) {
            bf16x8 bfrag = *(const bf16x8*)(x1Row + s * 32 + q * 8);
#pragma unroll
            for (int nt = 0; nt < 4; ++nt) {
                bf16x8 afrag = *(const bf16x8*)(sW2 + (16 * nt + m) * W2S + s * 32 + q * 8);
                acc2[nt] = __builtin_amdgcn_mfma_f32_16x16x32_bf16(afrag, bfrag, acc2[nt], 0, 0, 0);
            }
        }

        // ---------- epilogue: scal = silu(X2) . W3, all in registers ----------
        float p = 0.f;
#pragma unroll
        for (int nt = 0; nt < 4; ++nt) {
            float4 b2v = *(const float4*)(&sB2[16 * nt + 4 * q]);
            float4 w3v = *(const float4*)(&sW3[16 * nt + 4 * q]);
            p = fmaf(silu_f(acc2[nt][0] + b2v.x), w3v.x, p);
            p = fmaf(silu_f(acc2[nt][1] + b2v.y), w3v.y, p);
            p = fmaf(silu_f(acc2[nt][2] + b2v.z), w3v.z, p);
            p = fmaf(silu_f(acc2[nt][3] + b2v.w), w3v.w, p);
        }
        p += __shfl_xor(p, 16);
        p += __shfl_xor(p, 32);

        // distributed coord-diff: lane (q,m) owns component q of edge m
        float cd = cr_c - cc_c;                    // q==3 lanes contribute 0
        float r2 = cd * cd;
        r2 += __shfl_xor(r2, 16);
        r2 += __shfl_xor(r2, 32);
        if (e_c < E_ && q < 3) {
            float inv = __builtin_amdgcn_rcpf(sqrtf(r2 + 1e-8f) + 1.0f);
            atomicAdd(&out[row_c * 3 + q], cd * (p * NORM_INV * inv));
        }

        // -------- rotate pipeline (named-register moves) --------
        e_c = e_n; row_c = row_n; col_c = col_n;
        cr_c = cr_n; cc_c = cc_n;
        f0 = n0; f1 = n1; f2 = n2; f3 = n3; f4 = n4;
        e_n = e_n2; row_n = row_n2; col_n = col_n2;
    }
}

extern "C" void kernel_launch(void* const* d_in, const int* in_sizes, int n_in,
                              void* d_out, int out_size, void* d_ws, size_t ws_size,
                              hipStream_t stream) {
    const float* h         = (const float*)d_in[0];
    const float* coord     = (const float*)d_in[1];
    const int*   eidx      = (const int*)  d_in[2];
    const float* edge_attr = (const float*)d_in[3];
    const float* W1        = (const float*)d_in[4];
    const float* b1        = (const float*)d_in[5];
    const float* W2        = (const float*)d_in[6];
    const float* b2        = (const float*)d_in[7];
    const float* W3        = (const float*)d_in[8];
    float* out = (float*)d_out;

    int E_ = in_sizes[2] / 2;    // edge_index is [2, E]
    int n3 = out_size;           // N*3
    int nf = in_sizes[0];        // N*HD floats of h

    if (ws_size >= (size_t)nf * 2) {             // bf16 h table (6.4 MB)
        unsigned short* hbf = (unsigned short*)d_ws;
        int npairs = nf / 2;
        int pgrid = (npairs > n3 ? npairs : n3);
        hipLaunchKernelGGL(prep_h_kernel, dim3((pgrid + 255) / 256), dim3(256), 0, stream,
                           h, hbf, npairs, coord, out, n3);
        hipLaunchKernelGGL((egnn_mfma_kernel<true>), dim3(NBLK), dim3(NTH), 0, stream,
                           h, hbf, coord, eidx, edge_attr, W1, W2, b1, b2, W3, out, E_);
    } else {
        hipLaunchKernelGGL(prep_out_kernel, dim3((n3 + 255) / 256), dim3(256), 0, stream,
                           coord, out, n3);
        hipLaunchKernelGGL((egnn_mfma_kernel<false>), dim3(NBLK), dim3(NTH), 0, stream,
                           h, (const unsigned short*)nullptr, coord, eidx, edge_attr,
                           W1, W2, b1, b2, W3, out, E_);
    }
}

// Round 3
// 504.900 us; speedup vs baseline: 1.1968x; 1.1968x over previous
//
#include <hip/hip_runtime.h>
#include <math.h>

#define HD   64
#define EIN  8
#define SAS  168          // sW1 row stride in u16 (336 B): bank step 20 -> conflict-light
#define W2S  72           // sW2/X1 row stride in u16 (144 B)
#define NORM_INV 0.01f
#define NTH  256          // 4 waves/block
#define NBLK 1024         // r8: 4 blocks/CU x 256 CUs (LDS 4 x 40960 B = exactly 160 KiB)
#define NWAVES (NBLK * (NTH / 64))

typedef short bf16x8 __attribute__((ext_vector_type(8)));
typedef float f32x4  __attribute__((ext_vector_type(4)));
typedef float f4v    __attribute__((ext_vector_type(4)));

__device__ __forceinline__ unsigned short f2bf(float f) {
    union { float f; unsigned u; } v; v.f = f;
    unsigned r = v.u + 0x7FFFu + ((v.u >> 16) & 1u);
    return (unsigned short)(r >> 16);
}
__device__ __forceinline__ unsigned pk2(float a, float b) {
    return (unsigned)f2bf(a) | ((unsigned)f2bf(b) << 16);
}
__device__ __forceinline__ float silu_f(float x) {
    return x * __builtin_amdgcn_rcpf(1.0f + __expf(-x));
}

// prep: h -> bf16 table in ws + coord -> out copy
__global__ void prep_h_kernel(const float* __restrict__ h, unsigned short* __restrict__ hbf,
                              int npairs, const float* __restrict__ coord,
                              float* __restrict__ out, int n3) {
    int i = blockIdx.x * blockDim.x + threadIdx.x;
    if (i < npairs) {
        float2 v = reinterpret_cast<const float2*>(h)[i];
        ushort2 o; o.x = f2bf(v.x); o.y = f2bf(v.y);
        reinterpret_cast<ushort2*>(hbf)[i] = o;
    }
    if (i < n3) out[i] = coord[i];
}

__global__ void prep_out_kernel(const float* __restrict__ coord,
                                float* __restrict__ out, int n3) {
    int i = blockIdx.x * blockDim.x + threadIdx.x;
    if (i < n3) out[i] = coord[i];
}

// r8: post-mortem of r6/r7 -- the 2-deep cross-iteration pipeline was demoted
// to scratch no matter how it was spelled (VGPR 84->64 while ADDING state,
// FETCH +870 MB = spill round-trips; 277 -> 510 us). Cross-iteration fragment
// pipelining is dead. This round isolates the ONE lever that mechanically
// worked in r6/r7 (occupancy 34 -> 46%) on the known-good r5 body:
// launch_bounds(256,4) + grid 1024 = 4 blocks/CU, LDS exactly 160 KiB/CU.
// r5 body is 84 VGPR <= 128 cap at 4 waves/EU -> spill-free by construction.
template <bool HB>
__global__ __launch_bounds__(NTH, 4) void egnn_mfma_kernel(
    const float* __restrict__ h,             // fp32 h (when !HB)
    const unsigned short* __restrict__ hbf,  // bf16 h table in ws (when HB)
    const float* __restrict__ coord,
    const int*   __restrict__ eidx,   // [2][E]
    const float* __restrict__ eattr,  // [E][8]
    const float* __restrict__ W1f,    // [136][64] fp32
    const float* __restrict__ W2f,    // [64][64] fp32
    const float* __restrict__ b1,
    const float* __restrict__ b2,
    const float* __restrict__ W3,
    float* __restrict__ out,
    int E_)
{
    __shared__ unsigned short sW1[64 * SAS];      // 21504 B
    __shared__ unsigned short sW2[64 * W2S];      //  9216 B
    __shared__ unsigned short sX1[64 * W2S];      //  9216 B (4 waves x 16 rows)
    __shared__ float sB1[64], sB2[64], sW3[64];   //   768 B

    const int t = threadIdx.x;

    // ---- weights -> LDS (once per block) ----
    for (int i = t; i < 136 * 64; i += NTH) {
        int k = i >> 6, n = i & 63;
        sW1[n * SAS + k] = f2bf(W1f[i]);
    }
    for (int i = t; i < 24 * 64; i += NTH) {      // zero-pad W1 k=136..159
        int n = i / 24, k = 136 + (i - n * 24);
        sW1[n * SAS + k] = 0;
    }
    for (int i = t; i < 64 * 64; i += NTH) {
        int k = i >> 6, n = i & 63;
        sW2[n * W2S + k] = f2bf(W2f[i]);
    }
    if (t < 64) sB1[t] = b1[t];
    else if (t < 128) sB2[t - 64] = b2[t - 64];
    else if (t < 192) sW3[t - 128] = W3[t - 128];
    __syncthreads();                               // the ONLY barrier

    const int w = t >> 6, lane = t & 63;
    const int m = lane & 15, q = lane >> 4;

    unsigned short* x1Row = sX1 + (16 * w + m) * W2S;  // this lane's edge row

    const int ngroups = (E_ + 15) >> 4;
    for (int g = blockIdx.x * (NTH / 64) + w; g < ngroups; g += NWAVES) {
        // ---------- per-lane edge indices (each lane owns edge m of group) ----------
        int e = g * 16 + m;
        int ec = (e < E_) ? e : (E_ - 1);
        int row = eidx[ec];
        int col = eidx[(size_t)E_ + ec];

        // coord loads issued early (latency hidden behind MFMA)
        float cr = 0.f, cc = 0.f;
        if (q < 3) { cr = coord[row * 3 + q]; cc = coord[col * 3 + q]; }

        // ---------- layer-1 B-fragments: one 16 B gather each ----------
        bf16x8 bf[5];
        if (HB) {
            const bf16x8* hr = (const bf16x8*)(hbf + (size_t)row * HD);
            const bf16x8* hc = (const bf16x8*)(hbf + (size_t)col * HD);
            bf[0] = hr[q];          // k =   q*8 .. +8
            bf[1] = hr[4 + q];      // k = 32+q*8
            bf[2] = hc[q];          // k = 64+...
            bf[3] = hc[4 + q];      // k = 96+...
        } else {
            const f4v* hr = (const f4v*)(h + (size_t)row * HD);
            const f4v* hc = (const f4v*)(h + (size_t)col * HD);
#pragma unroll
            for (int s = 0; s < 4; ++s) {
                const f4v* src = (s < 2) ? hr : hc;
                f4v a = src[(s & 1) * 8 + q * 2];
                f4v b = src[(s & 1) * 8 + q * 2 + 1];
                union { bf16x8 v; uint4 u; } pk;
                pk.u.x = pk2(a.x, a.y); pk.u.y = pk2(a.z, a.w);
                pk.u.z = pk2(b.x, b.y); pk.u.w = pk2(b.z, b.w);
                bf[s] = pk.v;
            }
        }
        {
            union { bf16x8 v; uint4 u; } pk;
            pk.u.x = 0; pk.u.y = 0; pk.u.z = 0; pk.u.w = 0;
            if (q == 0) {                       // k = 128..135: edge_attr
                f4v a0 = ((const f4v*)(eattr + (size_t)ec * EIN))[0];
                f4v a1 = ((const f4v*)(eattr + (size_t)ec * EIN))[1];
                pk.u.x = pk2(a0.x, a0.y); pk.u.y = pk2(a0.z, a0.w);
                pk.u.z = pk2(a1.x, a1.y); pk.u.w = pk2(a1.z, a1.w);
            }
            bf[4] = pk.v;                       // q>0: zeros (W1 pad also zero)
        }

        // ---------- layer 1: D1[n2][e] = sum_k W1[n2][k] * inp[e][k] ----------
        f32x4 acc1[4] = {};
#pragma unroll
        for (int s = 0; s < 5; ++s) {
#pragma unroll
            for (int nt = 0; nt < 4; ++nt) {
                bf16x8 afrag = *(const bf16x8*)(sW1 + (16 * nt + m) * SAS + s * 32 + q * 8);
                acc1[nt] = __builtin_amdgcn_mfma_f32_16x16x32_bf16(afrag, bf[s], acc1[nt], 0, 0, 0);
            }
        }

        // silu(+b1) -> X1[e][k] packed b64 per lane
#pragma unroll
        for (int nt = 0; nt < 4; ++nt) {
            float4 bb = *(const float4*)(&sB1[16 * nt + 4 * q]);
            ushort4 o;
            o.x = f2bf(silu_f(acc1[nt][0] + bb.x));
            o.y = f2bf(silu_f(acc1[nt][1] + bb.y));
            o.z = f2bf(silu_f(acc1[nt][2] + bb.z));
            o.w = f2bf(silu_f(acc1[nt][3] + bb.w));
            *((ushort4*)(x1Row + 16 * nt + 4 * q)) = o;
        }

        // ---------- layer 2: D2[n2][e] = sum_k W2[n2][k] * X1[e][k] ----------
        f32x4 acc2[4] = {};
#pragma unroll
        for (int s = 0; s < 2; ++s) {
            bf16x8 bfrag = *(const bf16x8*)(x1Row + s * 32 + q * 8);
#pragma unroll
            for (int nt = 0; nt < 4; ++nt) {
                bf16x8 afrag = *(const bf16x8*)(sW2 + (16 * nt + m) * W2S + s * 32 + q * 8);
                acc2[nt] = __builtin_amdgcn_mfma_f32_16x16x32_bf16(afrag, bfrag, acc2[nt], 0, 0, 0);
            }
        }

        // ---------- epilogue: scal = silu(X2) . W3, all in registers ----------
        float p = 0.f;
#pragma unroll
        for (int nt = 0; nt < 4; ++nt) {
            float4 b2v = *(const float4*)(&sB2[16 * nt + 4 * q]);
            float4 w3v = *(const float4*)(&sW3[16 * nt + 4 * q]);
            p = fmaf(silu_f(acc2[nt][0] + b2v.x), w3v.x, p);
            p = fmaf(silu_f(acc2[nt][1] + b2v.y), w3v.y, p);
            p = fmaf(silu_f(acc2[nt][2] + b2v.z), w3v.z, p);
            p = fmaf(silu_f(acc2[nt][3] + b2v.w), w3v.w, p);
        }
        p += __shfl_xor(p, 16);
        p += __shfl_xor(p, 32);

        // distributed coord-diff: lane (q,m) owns component q of edge m
        float cd = cr - cc;                        // q==3 lanes contribute 0
        float r2 = cd * cd;
        r2 += __shfl_xor(r2, 16);
        r2 += __shfl_xor(r2, 32);
        if (e < E_ && q < 3) {
            float inv = __builtin_amdgcn_rcpf(sqrtf(r2 + 1e-8f) + 1.0f);
            atomicAdd(&out[row * 3 + q], cd * (p * NORM_INV * inv));
        }
    }
}

extern "C" void kernel_launch(void* const* d_in, const int* in_sizes, int n_in,
                              void* d_out, int out_size, void* d_ws, size_t ws_size,
                              hipStream_t stream) {
    const float* h         = (const float*)d_in[0];
    const float* coord     = (const float*)d_in[1];
    const int*   eidx      = (const int*)  d_in[2];
    const float* edge_attr = (const float*)d_in[3];
    const float* W1        = (const float*)d_in[4];
    const float* b1        = (const float*)d_in[5];
    const float* W2        = (const float*)d_in[6];
    const float* b2        = (const float*)d_in[7];
    const float* W3        = (const float*)d_in[8];
    float* out = (float*)d_out;

    int E_ = in_sizes[2] / 2;    // edge_index is [2, E]
    int n3 = out_size;           // N*3
    int nf = in_sizes[0];        // N*HD floats of h

    if (ws_size >= (size_t)nf * 2) {             // bf16 h table (6.4 MB)
        unsigned short* hbf = (unsigned short*)d_ws;
        int npairs = nf / 2;
        int pgrid = (npairs > n3 ? npairs : n3);
        hipLaunchKernelGGL(prep_h_kernel, dim3((pgrid + 255) / 256), dim3(256), 0, stream,
                           h, hbf, npairs, coord, out, n3);
        hipLaunchKernelGGL((egnn_mfma_kernel<true>), dim3(NBLK), dim3(NTH), 0, stream,
                           h, hbf, coord, eidx, edge_attr, W1, W2, b1, b2, W3, out, E_);
    } else {
        hipLaunchKernelGGL(prep_out_kernel, dim3((n3 + 255) / 256), dim3(256), 0, stream,
                           coord, out, n3);
        hipLaunchKernelGGL((egnn_mfma_kernel<false>), dim3(NBLK), dim3(NTH), 0, stream,
                           h, (const unsigned short*)nullptr, coord, eidx, edge_attr,
                           W1, W2, b1, b2, W3, out, E_);
    }
}

// Round 4
// 466.202 us; speedup vs baseline: 1.2962x; 1.0830x over previous
//
#include <hip/hip_runtime.h>
#include <math.h>

#define HD   64
#define EIN  8
#define SAS  168          // sW1 row stride in u16 (336 B): bank step 20 -> conflict-light
#define W2S  72           // sW2/X1 row stride in u16 (144 B)
#define NORM_INV 0.01f
#define NTH  256          // 4 waves/block
#define NBLK 1024         // r9: 4 blocks/CU via GRID, not launch_bounds
#define NWAVES (NBLK * (NTH / 64))

typedef short bf16x8 __attribute__((ext_vector_type(8)));
typedef float f32x4  __attribute__((ext_vector_type(4)));
typedef float f4v    __attribute__((ext_vector_type(4)));

__device__ __forceinline__ unsigned short f2bf(float f) {
    union { float f; unsigned u; } v; v.f = f;
    unsigned r = v.u + 0x7FFFu + ((v.u >> 16) & 1u);
    return (unsigned short)(r >> 16);
}
__device__ __forceinline__ unsigned pk2(float a, float b) {
    return (unsigned)f2bf(a) | ((unsigned)f2bf(b) << 16);
}
__device__ __forceinline__ float silu_f(float x) {
    return x * __builtin_amdgcn_rcpf(1.0f + __expf(-x));
}

// prep: h -> bf16 table in ws + coord -> out copy
__global__ void prep_h_kernel(const float* __restrict__ h, unsigned short* __restrict__ hbf,
                              int npairs, const float* __restrict__ coord,
                              float* __restrict__ out, int n3) {
    int i = blockIdx.x * blockDim.x + threadIdx.x;
    if (i < npairs) {
        float2 v = reinterpret_cast<const float2*>(h)[i];
        ushort2 o; o.x = f2bf(v.x); o.y = f2bf(v.y);
        reinterpret_cast<ushort2*>(hbf)[i] = o;
    }
    if (i < n3) out[i] = coord[i];
}

__global__ void prep_out_kernel(const float* __restrict__ coord,
                                float* __restrict__ out, int n3) {
    int i = blockIdx.x * blockDim.x + threadIdx.x;
    if (i < n3) out[i] = coord[i];
}

// r9: post-mortem of r8 -- launch_bounds(256,4) ITSELF caused the spill
// (allocator clamps arch-VGPR to 64 inside the 4-wave envelope; r5 body needs
// 84 -> ~20 regs of per-iteration scratch -> +530 MB FETCH, 407 us). The
// occupancy gain never needed the bound: at 84 VGPR (88-granule -> 5 waves/
// SIMD possible) and 40960 B LDS (exactly 4 blocks/CU), FOUR blocks fit with
// the spill-free codegen. r5 ran 3 blocks/CU only because NBLK=768 was the
// limiter. Fix: keep launch_bounds(256,3) (proven 84-VGPR codegen), raise the
// grid to 1024 = 4 blocks/CU. Hardware packs what fits.
template <bool HB>
__global__ __launch_bounds__(NTH, 3) void egnn_mfma_kernel(
    const float* __restrict__ h,             // fp32 h (when !HB)
    const unsigned short* __restrict__ hbf,  // bf16 h table in ws (when HB)
    const float* __restrict__ coord,
    const int*   __restrict__ eidx,   // [2][E]
    const float* __restrict__ eattr,  // [E][8]
    const float* __restrict__ W1f,    // [136][64] fp32
    const float* __restrict__ W2f,    // [64][64] fp32
    const float* __restrict__ b1,
    const float* __restrict__ b2,
    const float* __restrict__ W3,
    float* __restrict__ out,
    int E_)
{
    __shared__ unsigned short sW1[64 * SAS];      // 21504 B
    __shared__ unsigned short sW2[64 * W2S];      //  9216 B
    __shared__ unsigned short sX1[64 * W2S];      //  9216 B (4 waves x 16 rows)
    __shared__ float sB1[64], sB2[64], sW3[64];   //   768 B

    const int t = threadIdx.x;

    // ---- weights -> LDS (once per block) ----
    for (int i = t; i < 136 * 64; i += NTH) {
        int k = i >> 6, n = i & 63;
        sW1[n * SAS + k] = f2bf(W1f[i]);
    }
    for (int i = t; i < 24 * 64; i += NTH) {      // zero-pad W1 k=136..159
        int n = i / 24, k = 136 + (i - n * 24);
        sW1[n * SAS + k] = 0;
    }
    for (int i = t; i < 64 * 64; i += NTH) {
        int k = i >> 6, n = i & 63;
        sW2[n * W2S + k] = f2bf(W2f[i]);
    }
    if (t < 64) sB1[t] = b1[t];
    else if (t < 128) sB2[t - 64] = b2[t - 64];
    else if (t < 192) sW3[t - 128] = W3[t - 128];
    __syncthreads();                               // the ONLY barrier

    const int w = t >> 6, lane = t & 63;
    const int m = lane & 15, q = lane >> 4;

    unsigned short* x1Row = sX1 + (16 * w + m) * W2S;  // this lane's edge row

    const int ngroups = (E_ + 15) >> 4;
    for (int g = blockIdx.x * (NTH / 64) + w; g < ngroups; g += NWAVES) {
        // ---------- per-lane edge indices (each lane owns edge m of group) ----------
        int e = g * 16 + m;
        int ec = (e < E_) ? e : (E_ - 1);
        int row = eidx[ec];
        int col = eidx[(size_t)E_ + ec];

        // coord loads issued early (latency hidden behind MFMA)
        float cr = 0.f, cc = 0.f;
        if (q < 3) { cr = coord[row * 3 + q]; cc = coord[col * 3 + q]; }

        // ---------- layer-1 B-fragments: one 16 B gather each ----------
        bf16x8 bf[5];
        if (HB) {
            const bf16x8* hr = (const bf16x8*)(hbf + (size_t)row * HD);
            const bf16x8* hc = (const bf16x8*)(hbf + (size_t)col * HD);
            bf[0] = hr[q];          // k =   q*8 .. +8
            bf[1] = hr[4 + q];      // k = 32+q*8
            bf[2] = hc[q];          // k = 64+...
            bf[3] = hc[4 + q];      // k = 96+...
        } else {
            const f4v* hr = (const f4v*)(h + (size_t)row * HD);
            const f4v* hc = (const f4v*)(h + (size_t)col * HD);
#pragma unroll
            for (int s = 0; s < 4; ++s) {
                const f4v* src = (s < 2) ? hr : hc;
                f4v a = src[(s & 1) * 8 + q * 2];
                f4v b = src[(s & 1) * 8 + q * 2 + 1];
                union { bf16x8 v; uint4 u; } pk;
                pk.u.x = pk2(a.x, a.y); pk.u.y = pk2(a.z, a.w);
                pk.u.z = pk2(b.x, b.y); pk.u.w = pk2(b.z, b.w);
                bf[s] = pk.v;
            }
        }
        {
            union { bf16x8 v; uint4 u; } pk;
            pk.u.x = 0; pk.u.y = 0; pk.u.z = 0; pk.u.w = 0;
            if (q == 0) {                       // k = 128..135: edge_attr
                f4v a0 = ((const f4v*)(eattr + (size_t)ec * EIN))[0];
                f4v a1 = ((const f4v*)(eattr + (size_t)ec * EIN))[1];
                pk.u.x = pk2(a0.x, a0.y); pk.u.y = pk2(a0.z, a0.w);
                pk.u.z = pk2(a1.x, a1.y); pk.u.w = pk2(a1.z, a1.w);
            }
            bf[4] = pk.v;                       // q>0: zeros (W1 pad also zero)
        }

        // ---------- layer 1: D1[n2][e] = sum_k W1[n2][k] * inp[e][k] ----------
        f32x4 acc1[4] = {};
#pragma unroll
        for (int s = 0; s < 5; ++s) {
#pragma unroll
            for (int nt = 0; nt < 4; ++nt) {
                bf16x8 afrag = *(const bf16x8*)(sW1 + (16 * nt + m) * SAS + s * 32 + q * 8);
                acc1[nt] = __builtin_amdgcn_mfma_f32_16x16x32_bf16(afrag, bf[s], acc1[nt], 0, 0, 0);
            }
        }

        // silu(+b1) -> X1[e][k] packed b64 per lane
#pragma unroll
        for (int nt = 0; nt < 4; ++nt) {
            float4 bb = *(const float4*)(&sB1[16 * nt + 4 * q]);
            ushort4 o;
            o.x = f2bf(silu_f(acc1[nt][0] + bb.x));
            o.y = f2bf(silu_f(acc1[nt][1] + bb.y));
            o.z = f2bf(silu_f(acc1[nt][2] + bb.z));
            o.w = f2bf(silu_f(acc1[nt][3] + bb.w));
            *((ushort4*)(x1Row + 16 * nt + 4 * q)) = o;
        }

        // ---------- layer 2: D2[n2][e] = sum_k W2[n2][k] * X1[e][k] ----------
        f32x4 acc2[4] = {};
#pragma unroll
        for (int s = 0; s < 2; ++s) {
            bf16x8 bfrag = *(const bf16x8*)(x1Row + s * 32 + q * 8);
#pragma unroll
            for (int nt = 0; nt < 4; ++nt) {
                bf16x8 afrag = *(const bf16x8*)(sW2 + (16 * nt + m) * W2S + s * 32 + q * 8);
                acc2[nt] = __builtin_amdgcn_mfma_f32_16x16x32_bf16(afrag, bfrag, acc2[nt], 0, 0, 0);
            }
        }

        // ---------- epilogue: scal = silu(X2) . W3, all in registers ----------
        float p = 0.f;
#pragma unroll
        for (int nt = 0; nt < 4; ++nt) {
            float4 b2v = *(const float4*)(&sB2[16 * nt + 4 * q]);
            float4 w3v = *(const float4*)(&sW3[16 * nt + 4 * q]);
            p = fmaf(silu_f(acc2[nt][0] + b2v.x), w3v.x, p);
            p = fmaf(silu_f(acc2[nt][1] + b2v.y), w3v.y, p);
            p = fmaf(silu_f(acc2[nt][2] + b2v.z), w3v.z, p);
            p = fmaf(silu_f(acc2[nt][3] + b2v.w), w3v.w, p);
        }
        p += __shfl_xor(p, 16);
        p += __shfl_xor(p, 32);

        // distributed coord-diff: lane (q,m) owns component q of edge m
        float cd = cr - cc;                        // q==3 lanes contribute 0
        float r2 = cd * cd;
        r2 += __shfl_xor(r2, 16);
        r2 += __shfl_xor(r2, 32);
        if (e < E_ && q < 3) {
            float inv = __builtin_amdgcn_rcpf(sqrtf(r2 + 1e-8f) + 1.0f);
            atomicAdd(&out[row * 3 + q], cd * (p * NORM_INV * inv));
        }
    }
}

extern "C" void kernel_launch(void* const* d_in, const int* in_sizes, int n_in,
                              void* d_out, int out_size, void* d_ws, size_t ws_size,
                              hipStream_t stream) {
    const float* h         = (const float*)d_in[0];
    const float* coord     = (const float*)d_in[1];
    const int*   eidx      = (const int*)  d_in[2];
    const float* edge_attr = (const float*)d_in[3];
    const float* W1        = (const float*)d_in[4];
    const float* b1        = (const float*)d_in[5];
    const float* W2        = (const float*)d_in[6];
    const float* b2        = (const float*)d_in[7];
    const float* W3        = (const float*)d_in[8];
    float* out = (float*)d_out;

    int E_ = in_sizes[2] / 2;    // edge_index is [2, E]
    int n3 = out_size;           // N*3
    int nf = in_sizes[0];        // N*HD floats of h

    if (ws_size >= (size_t)nf * 2) {             // bf16 h table (6.4 MB)
        unsigned short* hbf = (unsigned short*)d_ws;
        int npairs = nf / 2;
        int pgrid = (npairs > n3 ? npairs : n3);
        hipLaunchKernelGGL(prep_h_kernel, dim3((pgrid + 255) / 256), dim3(256), 0, stream,
                           h, hbf, npairs, coord, out, n3);
        hipLaunchKernelGGL((egnn_mfma_kernel<true>), dim3(NBLK), dim3(NTH), 0, stream,
                           h, hbf, coord, eidx, edge_attr, W1, W2, b1, b2, W3, out, E_);
    } else {
        hipLaunchKernelGGL(prep_out_kernel, dim3((n3 + 255) / 256), dim3(256), 0, stream,
                           coord, out, n3);
        hipLaunchKernelGGL((egnn_mfma_kernel<false>), dim3(NBLK), dim3(NTH), 0, stream,
                           h, (const unsigned short*)nullptr, coord, eidx, edge_attr,
                           W1, W2, b1, b2, W3, out, E_);
    }
}

// Round 5
// 464.356 us; speedup vs baseline: 1.3013x; 1.0040x over previous
//
#include <hip/hip_runtime.h>
#include <math.h>

#define HD   64
#define EIN  8
#define SAS  168          // sW1 row stride in u16 (336 B): bank step 20 -> conflict-light
#define W2S  72           // sW2/X1 row stride in u16 (144 B)
#define NORM_INV 0.01f
#define NTH  256          // 4 waves/block
#define NBLK 768          // r10: 3 blocks/CU is the TRUE residency cap (r9 post-mortem)
#define NWAVES (NBLK * (NTH / 64))

typedef short bf16x8 __attribute__((ext_vector_type(8)));
typedef float f32x4  __attribute__((ext_vector_type(4)));
typedef float f4v    __attribute__((ext_vector_type(4)));

__device__ __forceinline__ unsigned short f2bf(float f) {
    union { float f; unsigned u; } v; v.f = f;
    unsigned r = v.u + 0x7FFFu + ((v.u >> 16) & 1u);
    return (unsigned short)(r >> 16);
}
__device__ __forceinline__ unsigned pk2(float a, float b) {
    return (unsigned)f2bf(a) | ((unsigned)f2bf(b) << 16);
}
__device__ __forceinline__ float silu_f(float x) {
    return x * __builtin_amdgcn_rcpf(1.0f + __expf(-x));
}
__device__ __forceinline__ bf16x8 pack_f8(f4v a, f4v b) {
    union { bf16x8 v; uint4 u; } pk;
    pk.u.x = pk2(a.x, a.y); pk.u.y = pk2(a.z, a.w);
    pk.u.z = pk2(b.x, b.y); pk.u.w = pk2(b.z, b.w);
    return pk.v;
}

// prep: h -> bf16 table in ws + coord -> out copy
__global__ void prep_h_kernel(const float* __restrict__ h, unsigned short* __restrict__ hbf,
                              int npairs, const float* __restrict__ coord,
                              float* __restrict__ out, int n3) {
    int i = blockIdx.x * blockDim.x + threadIdx.x;
    if (i < npairs) {
        float2 v = reinterpret_cast<const float2*>(h)[i];
        ushort2 o; o.x = f2bf(v.x); o.y = f2bf(v.y);
        reinterpret_cast<ushort2*>(hbf)[i] = o;
    }
    if (i < n3) out[i] = coord[i];
}

__global__ void prep_out_kernel(const float* __restrict__ coord,
                                float* __restrict__ out, int n3) {
    int i = blockIdx.x * blockDim.x + threadIdx.x;
    if (i < n3) out[i] = coord[i];
}

// r10: session ledger --
//  r6 (pipeline, bounds4): 510us spill  | r7 (named-reg pipeline, bounds4): 510us spill
//  r8 (r5 body, bounds4):  407us spill  -> bounds(,4) ALONE clamps arch-VGPR to 64 + spill
//  r9 (r5 body, bounds3, grid1024): 374us, occ 23% -> only 3 blocks/CU EVER fit
//     (84 arch + ~48 acc AGPRs > 128/wave in unified file); grid 1024 = two-phase
//     straggler. TRUE config: bounds(,3) + NBLK=768.
//  => the r7 pipeline was never tested spill-free. This round: r7 pipeline at
//     bounds(,3)/768. Budget 512/3=170 regs/wave; pipeline ~110 arch + acc fits.
//  Keystone: VGPR_Count ~104-130 (64 = demoted again; 84 = state not held).

#define LOAD_IDX(G, EV, ROW, COL) do {                                  \
    EV = (G) * 16 + m;                                                  \
    int ec_ = (EV < E_) ? EV : (E_ - 1);                                \
    ROW = eidx[ec_];                                                    \
    COL = eidx[(size_t)E_ + ec_];                                       \
} while (0)

#define LOAD_FRAG(EV, ROW, COL, CR, CC, F0, F1, F2, F3, F4) do {        \
    CR = 0.f; CC = 0.f;                                                 \
    if (q < 3) { CR = coord[(ROW) * 3 + q]; CC = coord[(COL) * 3 + q]; }\
    if (HB) {                                                           \
        const bf16x8* hr_ = (const bf16x8*)(hbf + (size_t)(ROW) * HD);  \
        const bf16x8* hc_ = (const bf16x8*)(hbf + (size_t)(COL) * HD);  \
        F0 = hr_[q]; F1 = hr_[4 + q]; F2 = hc_[q]; F3 = hc_[4 + q];     \
    } else {                                                            \
        const f4v* hr_ = (const f4v*)(h + (size_t)(ROW) * HD);          \
        const f4v* hc_ = (const f4v*)(h + (size_t)(COL) * HD);          \
        F0 = pack_f8(hr_[q * 2],     hr_[q * 2 + 1]);                   \
        F1 = pack_f8(hr_[8 + q * 2], hr_[8 + q * 2 + 1]);               \
        F2 = pack_f8(hc_[q * 2],     hc_[q * 2 + 1]);                   \
        F3 = pack_f8(hc_[8 + q * 2], hc_[8 + q * 2 + 1]);               \
    }                                                                   \
    {                                                                   \
        int ec_ = ((EV) < E_) ? (EV) : (E_ - 1);                        \
        union { bf16x8 v; uint4 u; } pk_;                               \
        pk_.u.x = 0; pk_.u.y = 0; pk_.u.z = 0; pk_.u.w = 0;             \
        if (q == 0) {                                                   \
            f4v a0_ = ((const f4v*)(eattr + (size_t)ec_ * EIN))[0];     \
            f4v a1_ = ((const f4v*)(eattr + (size_t)ec_ * EIN))[1];     \
            pk_.u.x = pk2(a0_.x, a0_.y); pk_.u.y = pk2(a0_.z, a0_.w);   \
            pk_.u.z = pk2(a1_.x, a1_.y); pk_.u.w = pk2(a1_.z, a1_.w);   \
        }                                                               \
        F4 = pk_.v;                                                     \
    }                                                                   \
} while (0)

template <bool HB>
__global__ __launch_bounds__(NTH, 3) void egnn_mfma_kernel(
    const float* __restrict__ h,             // fp32 h (when !HB)
    const unsigned short* __restrict__ hbf,  // bf16 h table in ws (when HB)
    const float* __restrict__ coord,
    const int*   __restrict__ eidx,   // [2][E]
    const float* __restrict__ eattr,  // [E][8]
    const float* __restrict__ W1f,    // [136][64] fp32
    const float* __restrict__ W2f,    // [64][64] fp32
    const float* __restrict__ b1,
    const float* __restrict__ b2,
    const float* __restrict__ W3,
    float* __restrict__ out,
    int E_)
{
    __shared__ unsigned short sW1[64 * SAS];      // 21504 B
    __shared__ unsigned short sW2[64 * W2S];      //  9216 B
    __shared__ unsigned short sX1[64 * W2S];      //  9216 B (4 waves x 16 rows)
    __shared__ float sB1[64], sB2[64], sW3[64];   //   768 B

    const int t = threadIdx.x;

    // ---- weights -> LDS (once per block) ----
    for (int i = t; i < 136 * 64; i += NTH) {
        int k = i >> 6, n = i & 63;
        sW1[n * SAS + k] = f2bf(W1f[i]);
    }
    for (int i = t; i < 24 * 64; i += NTH) {      // zero-pad W1 k=136..159
        int n = i / 24, k = 136 + (i - n * 24);
        sW1[n * SAS + k] = 0;
    }
    for (int i = t; i < 64 * 64; i += NTH) {
        int k = i >> 6, n = i & 63;
        sW2[n * W2S + k] = f2bf(W2f[i]);
    }
    if (t < 64) sB1[t] = b1[t];
    else if (t < 128) sB2[t - 64] = b2[t - 64];
    else if (t < 192) sW3[t - 128] = W3[t - 128];
    __syncthreads();                               // the ONLY barrier

    const int w = t >> 6, lane = t & 63;
    const int m = lane & 15, q = lane >> 4;

    unsigned short* x1Row = sX1 + (16 * w + m) * W2S;  // this lane's edge row

    const int ngroups = (E_ + 15) >> 4;
    const int g0 = blockIdx.x * (NTH / 64) + w;

    // ---- pipeline state: ALL named registers ----
    int   e_c = 0, row_c = 0, col_c = 0;
    float cr_c = 0.f, cc_c = 0.f;
    bf16x8 f0 = {}, f1 = {}, f2 = {}, f3 = {}, f4 = {};
    int   e_n = 0, row_n = 0, col_n = 0;

    // ---- prologue: fill the pipeline ----
    if (g0 < ngroups) {
        LOAD_IDX(g0, e_c, row_c, col_c);
        LOAD_FRAG(e_c, row_c, col_c, cr_c, cc_c, f0, f1, f2, f3, f4);
        if (g0 + NWAVES < ngroups)
            LOAD_IDX(g0 + NWAVES, e_n, row_n, col_n);
    }

    for (int g = g0; g < ngroups; g += NWAVES) {
        const int gn = g + NWAVES;

        // -------- prefetch next group's gathers BEFORE compute --------
        float cr_n = 0.f, cc_n = 0.f;
        bf16x8 n0 = f0, n1 = f1, n2 = f2, n3 = f3, n4 = f4;
        if (gn < ngroups)
            LOAD_FRAG(e_n, row_n, col_n, cr_n, cc_n, n0, n1, n2, n3, n4);
        int e_n2 = 0, row_n2 = 0, col_n2 = 0;
        if (gn + NWAVES < ngroups)
            LOAD_IDX(gn + NWAVES, e_n2, row_n2, col_n2);

        // ---------- layer 1: D1[n2][e] = sum_k W1[n2][k] * inp[e][k] ----------
        f32x4 acc1[4] = {};
#define L1STEP(S, F)                                                          \
        _Pragma("unroll")                                                     \
        for (int nt = 0; nt < 4; ++nt) {                                      \
            bf16x8 afrag = *(const bf16x8*)(sW1 + (16 * nt + m) * SAS + (S) * 32 + q * 8); \
            acc1[nt] = __builtin_amdgcn_mfma_f32_16x16x32_bf16(afrag, F, acc1[nt], 0, 0, 0); \
        }
        L1STEP(0, f0)
        L1STEP(1, f1)
        L1STEP(2, f2)
        L1STEP(3, f3)
        L1STEP(4, f4)
#undef L1STEP

        // silu(+b1) -> X1[e][k] packed b64 per lane
#pragma unroll
        for (int nt = 0; nt < 4; ++nt) {
            float4 bb = *(const float4*)(&sB1[16 * nt + 4 * q]);
            ushort4 o;
            o.x = f2bf(silu_f(acc1[nt][0] + bb.x));
            o.y = f2bf(silu_f(acc1[nt][1] + bb.y));
            o.z = f2bf(silu_f(acc1[nt][2] + bb.z));
            o.w = f2bf(silu_f(acc1[nt][3] + bb.w));
            *((ushort4*)(x1Row + 16 * nt + 4 * q)) = o;
        }

        // ---------- layer 2: D2[n2][e] = sum_k W2[n2][k] * X1[e][k] ----------
        f32x4 acc2[4] = {};
#pragma unroll
        for (int s = 0; s < 2; ++s) {
            bf16x8 bfrag = *(const bf16x8*)(x1Row + s * 32 + q * 8);
#pragma unroll
            for (int nt = 0; nt < 4; ++nt) {
                bf16x8 afrag = *(const bf16x8*)(sW2 + (16 * nt + m) * W2S + s * 32 + q * 8);
                acc2[nt] = __builtin_amdgcn_mfma_f32_16x16x32_bf16(afrag, bfrag, acc2[nt], 0, 0, 0);
            }
        }

        // ---------- epilogue: scal = silu(X2) . W3, all in registers ----------
        float p = 0.f;
#pragma unroll
        for (int nt = 0; nt < 4; ++nt) {
            float4 b2v = *(const float4*)(&sB2[16 * nt + 4 * q]);
            float4 w3v = *(const float4*)(&sW3[16 * nt + 4 * q]);
            p = fmaf(silu_f(acc2[nt][0] + b2v.x), w3v.x, p);
            p = fmaf(silu_f(acc2[nt][1] + b2v.y), w3v.y, p);
            p = fmaf(silu_f(acc2[nt][2] + b2v.z), w3v.z, p);
            p = fmaf(silu_f(acc2[nt][3] + b2v.w), w3v.w, p);
        }
        p += __shfl_xor(p, 16);
        p += __shfl_xor(p, 32);

        // distributed coord-diff: lane (q,m) owns component q of edge m
        float cd = cr_c - cc_c;                    // q==3 lanes contribute 0
        float r2 = cd * cd;
        r2 += __shfl_xor(r2, 16);
        r2 += __shfl_xor(r2, 32);
        if (e_c < E_ && q < 3) {
            float inv = __builtin_amdgcn_rcpf(sqrtf(r2 + 1e-8f) + 1.0f);
            atomicAdd(&out[row_c * 3 + q], cd * (p * NORM_INV * inv));
        }

        // -------- rotate pipeline (named-register moves) --------
        e_c = e_n; row_c = row_n; col_c = col_n;
        cr_c = cr_n; cc_c = cc_n;
        f0 = n0; f1 = n1; f2 = n2; f3 = n3; f4 = n4;
        e_n = e_n2; row_n = row_n2; col_n = col_n2;
    }
}

extern "C" void kernel_launch(void* const* d_in, const int* in_sizes, int n_in,
                              void* d_out, int out_size, void* d_ws, size_t ws_size,
                              hipStream_t stream) {
    const float* h         = (const float*)d_in[0];
    const float* coord     = (const float*)d_in[1];
    const int*   eidx      = (const int*)  d_in[2];
    const float* edge_attr = (const float*)d_in[3];
    const float* W1        = (const float*)d_in[4];
    const float* b1        = (const float*)d_in[5];
    const float* W2        = (const float*)d_in[6];
    const float* b2        = (const float*)d_in[7];
    const float* W3        = (const float*)d_in[8];
    float* out = (float*)d_out;

    int E_ = in_sizes[2] / 2;    // edge_index is [2, E]
    int n3 = out_size;           // N*3
    int nf = in_sizes[0];        // N*HD floats of h

    if (ws_size >= (size_t)nf * 2) {             // bf16 h table (6.4 MB)
        unsigned short* hbf = (unsigned short*)d_ws;
        int npairs = nf / 2;
        int pgrid = (npairs > n3 ? npairs : n3);
        hipLaunchKernelGGL(prep_h_kernel, dim3((pgrid + 255) / 256), dim3(256), 0, stream,
                           h, hbf, npairs, coord, out, n3);
        hipLaunchKernelGGL((egnn_mfma_kernel<true>), dim3(NBLK), dim3(NTH), 0, stream,
                           h, hbf, coord, eidx, edge_attr, W1, W2, b1, b2, W3, out, E_);
    } else {
        hipLaunchKernelGGL(prep_out_kernel, dim3((n3 + 255) / 256), dim3(256), 0, stream,
                           coord, out, n3);
        hipLaunchKernelGGL((egnn_mfma_kernel<false>), dim3(NBLK), dim3(NTH), 0, stream,
                           h, (const unsigned short*)nullptr, coord, eidx, edge_attr,
                           W1, W2, b1, b2, W3, out, E_);
    }
}

// Round 6
// 251.207 us; speedup vs baseline: 2.4055x; 1.8485x over previous
//
#include <hip/hip_runtime.h>
#include <math.h>

#define HD   64
#define EIN  8
#define SAS  168          // !HB: full bf16 W1 row stride in u16
#define W1BS 40           // HB: bf16 W1 tail (k=128..159) row stride in u16 (80 B, 16-B aligned)
#define W2S  72           // sW2/X1 row stride in u16 (144 B)
#define NORM_INV 0.01f
#define NTH  256
#define NBLK 768          // 3 blocks/CU: the true residency cap (r9)
#define NWAVES (NBLK * (NTH / 64))

typedef short bf16x8 __attribute__((ext_vector_type(8)));
typedef float f32x4  __attribute__((ext_vector_type(4)));
typedef float f4v    __attribute__((ext_vector_type(4)));

__device__ __forceinline__ unsigned short f2bf(float f) {
    union { float f; unsigned u; } v; v.f = f;
    unsigned r = v.u + 0x7FFFu + ((v.u >> 16) & 1u);
    return (unsigned short)(r >> 16);
}
__device__ __forceinline__ unsigned pk2(float a, float b) {
    return (unsigned)f2bf(a) | ((unsigned)f2bf(b) << 16);
}
__device__ __forceinline__ float silu_f(float x) {
    return x * __builtin_amdgcn_rcpf(1.0f + __expf(-x));
}
__device__ __forceinline__ bf16x8 pack_f8(f4v a, f4v b) {
    union { bf16x8 v; uint4 u; } pk;
    pk.u.x = pk2(a.x, a.y); pk.u.y = pk2(a.z, a.w);
    pk.u.z = pk2(b.x, b.y); pk.u.w = pk2(b.z, b.w);
    return pk.v;
}

// prep: h -> fp8 e4m3 table in ws (3.2 MB -> fits 4 MB/XCD L2) + coord -> out copy
__global__ void prep_h_kernel(const float* __restrict__ h, unsigned char* __restrict__ hf8,
                              int nq, const float* __restrict__ coord,
                              float* __restrict__ out, int n3) {
    int i = blockIdx.x * blockDim.x + threadIdx.x;
    if (i < nq) {
        f4v v = reinterpret_cast<const f4v*>(h)[i];
        int p = __builtin_amdgcn_cvt_pk_fp8_f32(v.x, v.y, 0, false);
        p     = __builtin_amdgcn_cvt_pk_fp8_f32(v.z, v.w, p, true);
        reinterpret_cast<int*>(hf8)[i] = p;
    }
    if (i < n3) out[i] = coord[i];
}

__global__ void prep_out_kernel(const float* __restrict__ coord,
                                float* __restrict__ out, int n3) {
    int i = blockIdx.x * blockDim.x + threadIdx.x;
    if (i < n3) out[i] = coord[i];
}

// r11 ledger:
//  r6/r7/r10: cross-iteration fragment pipelining dead -- compiler spills
//    (bounds4) or REMATERIALIZES the gathers (r10: VGPR stuck 84, FETCH +340MB
//    from double-issued h loads). Scheduling levers exhausted.
//  r5 traffic budget (FETCH 800MB): h-gathers 410MB (6.4MB bf16 table thrashes
//    4MB/XCD L2 -> zero reuse), atomics ~190MB, streams 64MB, coord ~50MB.
//    2.9 TB/s on the L2-miss path = the binding resource.
//  r11: shrink table to fp8 e4m3 (3.2MB < 4MB L2 -> per-XCD resident, kills
//    the 410MB). Layer-1 h-part via mfma fp8 (W1 pre-scaled x8, acc x0.125),
//    eattr tail stays bf16 MFMA. nontemporal eidx/eattr to protect residency.
//  Keystone: FETCH ~350-450MB. Risk: absmax (fp8 ~6x layer-1 quant error).
template <bool HB>
__global__ __launch_bounds__(NTH, 3) void egnn_mfma_kernel(
    const float* __restrict__ h,             // fp32 h (when !HB)
    const unsigned char* __restrict__ hf8,   // fp8 h table in ws (when HB)
    const float* __restrict__ coord,
    const int*   __restrict__ eidx,   // [2][E]
    const float* __restrict__ eattr,  // [E][8]
    const float* __restrict__ W1f,    // [136][64] fp32 (k-major)
    const float* __restrict__ W2f,    // [64][64] fp32
    const float* __restrict__ b1,
    const float* __restrict__ b2,
    const float* __restrict__ W3,
    float* __restrict__ out,
    int E_)
{
    __shared__ __align__(16) char sW1raw[64 * SAS * 2];   // 21504 B (union: fp8 frags + bf16 tail | full bf16)
    __shared__ unsigned short sW2[64 * W2S];              //  9216 B
    __shared__ unsigned short sX1[64 * W2S];              //  9216 B
    __shared__ float sB1[64], sB2[64], sW3[64];           //   768 B

    const int t = threadIdx.x;

    unsigned long* sW1f8 = (unsigned long*)sW1raw;              // HB: 16 frags x 64 lanes x 8 B = 8192 B
    unsigned short* sW1b = (unsigned short*)(sW1raw + 8192);    // HB: 64 x W1BS u16 = 5120 B
    unsigned short* sW1  = (unsigned short*)sW1raw;             // !HB: full bf16 64 x SAS

    // ---- weights -> LDS (once per block) ----
    if (HB) {
        // fp8 W1 fragments, pre-arranged per (nt,s,lane): lane holds
        // W1s[n2=16nt+m][k = s*32 + q*8 .. +7], W1 scaled x8 into e4m3 range.
        for (int f = t; f < 16 * 64; f += NTH) {
            int frag = f >> 6, ln = f & 63;
            int nt = frag >> 2, s = frag & 3;
            int mm = ln & 15, qq = ln >> 4;
            int n2 = nt * 16 + mm, kb = s * 32 + qq * 8;
            unsigned long v = 0;
#pragma unroll
            for (int j = 0; j < 8; j += 2) {
                float a = W1f[(kb + j) * 64 + n2] * 8.0f;
                float b = W1f[(kb + j + 1) * 64 + n2] * 8.0f;
                int p = __builtin_amdgcn_cvt_pk_fp8_f32(a, b, 0, false);
                v |= ((unsigned long)(unsigned)(p & 0xFFFF)) << (j * 8);
            }
            sW1f8[f] = v;
        }
        // bf16 W1 tail rows k=128..159 (eattr + zero pad), row-major [n2][W1BS]
        for (int i = t; i < 64 * 32; i += NTH) {
            int n2 = i >> 5, kk = i & 31;
            int k = 128 + kk;
            sW1b[n2 * W1BS + kk] = (k < 136) ? f2bf(W1f[k * 64 + n2]) : (unsigned short)0;
        }
    } else {
        for (int i = t; i < 136 * 64; i += NTH) {
            int k = i >> 6, n = i & 63;
            sW1[n * SAS + k] = f2bf(W1f[i]);
        }
        for (int i = t; i < 24 * 64; i += NTH) {
            int n = i / 24, k = 136 + (i - n * 24);
            sW1[n * SAS + k] = 0;
        }
    }
    for (int i = t; i < 64 * 64; i += NTH) {
        int k = i >> 6, n = i & 63;
        sW2[n * W2S + k] = f2bf(W2f[i]);
    }
    if (t < 64) sB1[t] = b1[t];
    else if (t < 128) sB2[t - 64] = b2[t - 64];
    else if (t < 192) sW3[t - 128] = W3[t - 128];
    __syncthreads();                               // the ONLY barrier

    const int w = t >> 6, lane = t & 63;
    const int m = lane & 15, q = lane >> 4;

    unsigned short* x1Row = sX1 + (16 * w + m) * W2S;

    const int ngroups = (E_ + 15) >> 4;
    for (int g = blockIdx.x * (NTH / 64) + w; g < ngroups; g += NWAVES) {
        int e = g * 16 + m;
        int ec = (e < E_) ? e : (E_ - 1);
        int row = __builtin_nontemporal_load(eidx + ec);
        int col = __builtin_nontemporal_load(eidx + (size_t)E_ + ec);

        // coord loads issued early (L2-resident table)
        float cr = 0.f, cc = 0.f;
        if (q < 3) { cr = coord[row * 3 + q]; cc = coord[col * 3 + q]; }

        // ---------- eattr fragment (bf16, k=128..135 on q==0) ----------
        bf16x8 bf4;
        {
            union { bf16x8 v; uint4 u; } pk;
            pk.u.x = 0; pk.u.y = 0; pk.u.z = 0; pk.u.w = 0;
            if (q == 0) {
                const f4v* ea = (const f4v*)(eattr + (size_t)ec * EIN);
                f4v a0 = __builtin_nontemporal_load(ea);
                f4v a1 = __builtin_nontemporal_load(ea + 1);
                pk.u.x = pk2(a0.x, a0.y); pk.u.y = pk2(a0.z, a0.w);
                pk.u.z = pk2(a1.x, a1.y); pk.u.w = pk2(a1.z, a1.w);
            }
            bf4 = pk.v;
        }

        f32x4 acc1[4] = {};

        if (HB) {
            // ---------- layer-1 h-part: fp8 gathers (8 B each, L2-resident) ----------
            const unsigned long* hr8 = (const unsigned long*)(hf8 + (size_t)row * HD);
            const unsigned long* hc8 = (const unsigned long*)(hf8 + (size_t)col * HD);
            long b0 = (long)hr8[q];         // k =      q*8
            long b1v = (long)hr8[4 + q];    // k = 32 + q*8
            long b2v = (long)hc8[q];        // k = 64 + ...
            long b3v = (long)hc8[4 + q];    // k = 96 + ...
#define L1F8(S, B)                                                            \
            _Pragma("unroll")                                                 \
            for (int nt = 0; nt < 4; ++nt) {                                  \
                long a8 = (long)sW1f8[((nt << 2) | (S)) * 64 + lane];         \
                acc1[nt] = __builtin_amdgcn_mfma_f32_16x16x32_fp8_fp8(a8, B, acc1[nt], 0, 0, 0); \
            }
            L1F8(0, b0)
            L1F8(1, b1v)
            L1F8(2, b2v)
            L1F8(3, b3v)
#undef L1F8
            // undo W1 x8 pre-scale (exact)
#pragma unroll
            for (int nt = 0; nt < 4; ++nt) {
                acc1[nt][0] *= 0.125f; acc1[nt][1] *= 0.125f;
                acc1[nt][2] *= 0.125f; acc1[nt][3] *= 0.125f;
            }
            // eattr tail (bf16 MFMA, global k=128..159)
#pragma unroll
            for (int nt = 0; nt < 4; ++nt) {
                bf16x8 afb = *(const bf16x8*)(sW1b + (16 * nt + m) * W1BS + q * 8);
                acc1[nt] = __builtin_amdgcn_mfma_f32_16x16x32_bf16(afb, bf4, acc1[nt], 0, 0, 0);
            }
        } else {
            // fp32 h -> bf16 fragments (fallback path, unchanged)
            bf16x8 bf[5];
            const f4v* hr = (const f4v*)(h + (size_t)row * HD);
            const f4v* hc = (const f4v*)(h + (size_t)col * HD);
#pragma unroll
            for (int s = 0; s < 4; ++s) {
                const f4v* src = (s < 2) ? hr : hc;
                f4v a = src[(s & 1) * 8 + q * 2];
                f4v b = src[(s & 1) * 8 + q * 2 + 1];
                bf[s] = pack_f8(a, b);
            }
            bf[4] = bf4;
#pragma unroll
            for (int s = 0; s < 5; ++s) {
#pragma unroll
                for (int nt = 0; nt < 4; ++nt) {
                    bf16x8 afrag = *(const bf16x8*)(sW1 + (16 * nt + m) * SAS + s * 32 + q * 8);
                    acc1[nt] = __builtin_amdgcn_mfma_f32_16x16x32_bf16(afrag, bf[s], acc1[nt], 0, 0, 0);
                }
            }
        }

        // silu(+b1) -> X1[e][k] packed b64 per lane
#pragma unroll
        for (int nt = 0; nt < 4; ++nt) {
            float4 bb = *(const float4*)(&sB1[16 * nt + 4 * q]);
            ushort4 o;
            o.x = f2bf(silu_f(acc1[nt][0] + bb.x));
            o.y = f2bf(silu_f(acc1[nt][1] + bb.y));
            o.z = f2bf(silu_f(acc1[nt][2] + bb.z));
            o.w = f2bf(silu_f(acc1[nt][3] + bb.w));
            *((ushort4*)(x1Row + 16 * nt + 4 * q)) = o;
        }

        // ---------- layer 2 (bf16, unchanged) ----------
        f32x4 acc2[4] = {};
#pragma unroll
        for (int s = 0; s < 2; ++s) {
            bf16x8 bfrag = *(const bf16x8*)(x1Row + s * 32 + q * 8);
#pragma unroll
            for (int nt = 0; nt < 4; ++nt) {
                bf16x8 afrag = *(const bf16x8*)(sW2 + (16 * nt + m) * W2S + s * 32 + q * 8);
                acc2[nt] = __builtin_amdgcn_mfma_f32_16x16x32_bf16(afrag, bfrag, acc2[nt], 0, 0, 0);
            }
        }

        // ---------- epilogue ----------
        float p = 0.f;
#pragma unroll
        for (int nt = 0; nt < 4; ++nt) {
            float4 b2v2 = *(const float4*)(&sB2[16 * nt + 4 * q]);
            float4 w3v  = *(const float4*)(&sW3[16 * nt + 4 * q]);
            p = fmaf(silu_f(acc2[nt][0] + b2v2.x), w3v.x, p);
            p = fmaf(silu_f(acc2[nt][1] + b2v2.y), w3v.y, p);
            p = fmaf(silu_f(acc2[nt][2] + b2v2.z), w3v.z, p);
            p = fmaf(silu_f(acc2[nt][3] + b2v2.w), w3v.w, p);
        }
        p += __shfl_xor(p, 16);
        p += __shfl_xor(p, 32);

        float cd = cr - cc;
        float r2 = cd * cd;
        r2 += __shfl_xor(r2, 16);
        r2 += __shfl_xor(r2, 32);
        if (e < E_ && q < 3) {
            float inv = __builtin_amdgcn_rcpf(sqrtf(r2 + 1e-8f) + 1.0f);
            atomicAdd(&out[row * 3 + q], cd * (p * NORM_INV * inv));
        }
    }
}

extern "C" void kernel_launch(void* const* d_in, const int* in_sizes, int n_in,
                              void* d_out, int out_size, void* d_ws, size_t ws_size,
                              hipStream_t stream) {
    const float* h         = (const float*)d_in[0];
    const float* coord     = (const float*)d_in[1];
    const int*   eidx      = (const int*)  d_in[2];
    const float* edge_attr = (const float*)d_in[3];
    const float* W1        = (const float*)d_in[4];
    const float* b1        = (const float*)d_in[5];
    const float* W2        = (const float*)d_in[6];
    const float* b2        = (const float*)d_in[7];
    const float* W3        = (const float*)d_in[8];
    float* out = (float*)d_out;

    int E_ = in_sizes[2] / 2;    // edge_index is [2, E]
    int n3 = out_size;           // N*3
    int nf = in_sizes[0];        // N*HD floats of h

    if (ws_size >= (size_t)nf) {                 // fp8 h table (3.2 MB)
        unsigned char* hf8 = (unsigned char*)d_ws;
        int nq = nf / 4;
        int pgrid = (nq > n3 ? nq : n3);
        hipLaunchKernelGGL(prep_h_kernel, dim3((pgrid + 255) / 256), dim3(256), 0, stream,
                           h, hf8, nq, coord, out, n3);
        hipLaunchKernelGGL((egnn_mfma_kernel<true>), dim3(NBLK), dim3(NTH), 0, stream,
                           h, hf8, coord, eidx, edge_attr, W1, W2, b1, b2, W3, out, E_);
    } else {
        hipLaunchKernelGGL(prep_out_kernel, dim3((n3 + 255) / 256), dim3(256), 0, stream,
                           coord, out, n3);
        hipLaunchKernelGGL((egnn_mfma_kernel<false>), dim3(NBLK), dim3(NTH), 0, stream,
                           h, (const unsigned char*)nullptr, coord, eidx, edge_attr,
                           W1, W2, b1, b2, W3, out, E_);
    }
}

// Round 7
// 221.963 us; speedup vs baseline: 2.7224x; 1.1317x over previous
//
#include <hip/hip_runtime.h>
#include <math.h>

#define HD   64
#define EIN  8
#define SAS  168          // !HB: full bf16 W1 row stride in u16
#define W1BS 40           // HB: bf16 W1 tail (k=128..159) row stride in u16 (80 B, 16-B aligned)
#define W2S  72           // sW2/X1 row stride in u16 (144 B)
#define NORM_INV 0.01f
#define NTH  256
#define NBLK 1024         // r12: retry 4 blocks/CU -- LDS shrunk to ~32.5 KB/block
#define NWAVES (NBLK * (NTH / 64))

typedef short bf16x8 __attribute__((ext_vector_type(8)));
typedef float f32x4  __attribute__((ext_vector_type(4)));
typedef float f4v    __attribute__((ext_vector_type(4)));

__device__ __forceinline__ unsigned short f2bf(float f) {
    union { float f; unsigned u; } v; v.f = f;
    unsigned r = v.u + 0x7FFFu + ((v.u >> 16) & 1u);
    return (unsigned short)(r >> 16);
}
__device__ __forceinline__ unsigned pk2(float a, float b) {
    return (unsigned)f2bf(a) | ((unsigned)f2bf(b) << 16);
}
// single-instruction packed f32->2xbf16 (RNE, matches f2bf on finite vals)
__device__ __forceinline__ unsigned cvt_pk_bf16(float lo, float hi) {
    unsigned r;
    asm("v_cvt_pk_bf16_f32 %0, %1, %2" : "=v"(r) : "v"(lo), "v"(hi));
    return r;
}
__device__ __forceinline__ float silu_f(float x) {
    return x * __builtin_amdgcn_rcpf(1.0f + __expf(-x));
}
__device__ __forceinline__ bf16x8 pack_f8(f4v a, f4v b) {
    union { bf16x8 v; uint4 u; } pk;
    pk.u.x = pk2(a.x, a.y); pk.u.y = pk2(a.z, a.w);
    pk.u.z = pk2(b.x, b.y); pk.u.w = pk2(b.z, b.w);
    return pk.v;
}

// prep: h -> fp8 e4m3 table in ws (3.2 MB -> fits 4 MB/XCD L2) + coord -> out copy
__global__ void prep_h_kernel(const float* __restrict__ h, unsigned char* __restrict__ hf8,
                              int nq, const float* __restrict__ coord,
                              float* __restrict__ out, int n3) {
    int i = blockIdx.x * blockDim.x + threadIdx.x;
    if (i < nq) {
        f4v v = reinterpret_cast<const f4v*>(h)[i];
        int p = __builtin_amdgcn_cvt_pk_fp8_f32(v.x, v.y, 0, false);
        p     = __builtin_amdgcn_cvt_pk_fp8_f32(v.z, v.w, p, true);
        reinterpret_cast<int*>(hf8)[i] = p;
    }
    if (i < n3) out[i] = coord[i];
}

__global__ void prep_out_kernel(const float* __restrict__ coord,
                                float* __restrict__ out, int n3) {
    int i = blockIdx.x * blockDim.x + threadIdx.x;
    if (i < n3) out[i] = coord[i];
}

// r12 ledger:
//  r11 (fp8 L2-resident h-table): 277 -> 149 us kernel, FETCH 800 -> 83 MB.
//    Theory confirmed: L2-miss throughput was the binder. Now: VALUBusy 48%,
//    MfmaUtil 12.5%, HBM 13%, occ 32% -> latency-limited on L2-hit gathers.
//  r12 levers: (a) LDS 40960 -> 32512 B (HB path needs only 13312 B for W1)
//    + grid 1024: retry 4 blocks/CU. r9's failure is consistent with LDS
//    exact-fit (4x40960 = exactly 160 KiB); regs permit 4 waves (84+32acc=116
//    <= 128). launch_bounds stays (,3) -- the (,4) spelling spills (r8).
//    (b) VALU cut: v_cvt_pk_bf16_f32 for X1/eattr packs (48+32 -> 8+4 ops).
//    (c) s_setprio around MFMA clusters (barrier-free divergent waves = the
//    attn regime where it measured +4-7%, m191).
//  Keystones: LDS_Block_Size ~32768; occupancy ~44 (if ~25 + two-phase ->
//    LDS wasn't r9's limiter, revert grid to 768).
template <bool HB>
__global__ __launch_bounds__(NTH, 3) void egnn_mfma_kernel(
    const float* __restrict__ h,             // fp32 h (when !HB)
    const unsigned char* __restrict__ hf8,   // fp8 h table in ws (when HB)
    const float* __restrict__ coord,
    const int*   __restrict__ eidx,   // [2][E]
    const float* __restrict__ eattr,  // [E][8]
    const float* __restrict__ W1f,    // [136][64] fp32 (k-major)
    const float* __restrict__ W2f,    // [64][64] fp32
    const float* __restrict__ b1,
    const float* __restrict__ b2,
    const float* __restrict__ W3,
    float* __restrict__ out,
    int E_)
{
    // HB layout: [0,8192) fp8 W1 frags | [8192,13312) bf16 W1 tail |
    //            [13312,22528) sW2 | [22528,31744) sX1 | [31744,32512) biases
    // !HB layout: [0,21504) bf16 W1 | [21504,30720) sW2 | [30720,39936) sX1 | ...
    constexpr int LDS_BYTES = HB ? 32512 : 40704;
    __shared__ __align__(16) char lds[LDS_BYTES];

    unsigned long*  sW1f8 = (unsigned long*)lds;                         // HB
    unsigned short* sW1b  = (unsigned short*)(lds + 8192);               // HB
    unsigned short* sW1   = (unsigned short*)lds;                        // !HB
    unsigned short* sW2   = (unsigned short*)(lds + (HB ? 13312 : 21504));
    unsigned short* sX1   = (unsigned short*)(lds + (HB ? 22528 : 30720));
    float*          sB1   = (float*)(lds + (HB ? 31744 : 39936));
    float*          sB2   = sB1 + 64;
    float*          sW3   = sB1 + 128;

    const int t = threadIdx.x;

    // ---- weights -> LDS (once per block) ----
    if (HB) {
        // fp8 W1 fragments, per (nt,s,lane): lane holds
        // W1s[n2=16nt+m][k = s*32 + q*8 .. +7], W1 scaled x8 into e4m3 range.
        for (int f = t; f < 16 * 64; f += NTH) {
            int frag = f >> 6, ln = f & 63;
            int nt = frag >> 2, s = frag & 3;
            int mm = ln & 15, qq = ln >> 4;
            int n2 = nt * 16 + mm, kb = s * 32 + qq * 8;
            unsigned long v = 0;
#pragma unroll
            for (int j = 0; j < 8; j += 2) {
                float a = W1f[(kb + j) * 64 + n2] * 8.0f;
                float b = W1f[(kb + j + 1) * 64 + n2] * 8.0f;
                int p = __builtin_amdgcn_cvt_pk_fp8_f32(a, b, 0, false);
                v |= ((unsigned long)(unsigned)(p & 0xFFFF)) << (j * 8);
            }
            sW1f8[f] = v;
        }
        // bf16 W1 tail rows k=128..159 (eattr + zero pad), row-major [n2][W1BS]
        for (int i = t; i < 64 * 32; i += NTH) {
            int n2 = i >> 5, kk = i & 31;
            int k = 128 + kk;
            sW1b[n2 * W1BS + kk] = (k < 136) ? f2bf(W1f[k * 64 + n2]) : (unsigned short)0;
        }
    } else {
        for (int i = t; i < 136 * 64; i += NTH) {
            int k = i >> 6, n = i & 63;
            sW1[n * SAS + k] = f2bf(W1f[i]);
        }
        for (int i = t; i < 24 * 64; i += NTH) {
            int n = i / 24, k = 136 + (i - n * 24);
            sW1[n * SAS + k] = 0;
        }
    }
    for (int i = t; i < 64 * 64; i += NTH) {
        int k = i >> 6, n = i & 63;
        sW2[n * W2S + k] = f2bf(W2f[i]);
    }
    if (t < 64) sB1[t] = b1[t];
    else if (t < 128) sB2[t - 64] = b2[t - 64];
    else if (t < 192) sW3[t - 128] = W3[t - 128];
    __syncthreads();                               // the ONLY barrier

    const int w = t >> 6, lane = t & 63;
    const int m = lane & 15, q = lane >> 4;

    unsigned short* x1Row = sX1 + (16 * w + m) * W2S;

    const int ngroups = (E_ + 15) >> 4;
    for (int g = blockIdx.x * (NTH / 64) + w; g < ngroups; g += NWAVES) {
        int e = g * 16 + m;
        int ec = (e < E_) ? e : (E_ - 1);
        int row = __builtin_nontemporal_load(eidx + ec);
        int col = __builtin_nontemporal_load(eidx + (size_t)E_ + ec);

        // coord loads issued early (L2-resident table)
        float cr = 0.f, cc = 0.f;
        if (q < 3) { cr = coord[row * 3 + q]; cc = coord[col * 3 + q]; }

        // ---------- eattr fragment (bf16, k=128..135 on q==0) ----------
        bf16x8 bf4;
        {
            union { bf16x8 v; uint4 u; } pk;
            pk.u.x = 0; pk.u.y = 0; pk.u.z = 0; pk.u.w = 0;
            if (q == 0) {
                const f4v* ea = (const f4v*)(eattr + (size_t)ec * EIN);
                f4v a0 = __builtin_nontemporal_load(ea);
                f4v a1 = __builtin_nontemporal_load(ea + 1);
                pk.u.x = cvt_pk_bf16(a0.x, a0.y);
                pk.u.y = cvt_pk_bf16(a0.z, a0.w);
                pk.u.z = cvt_pk_bf16(a1.x, a1.y);
                pk.u.w = cvt_pk_bf16(a1.z, a1.w);
            }
            bf4 = pk.v;
        }

        f32x4 acc1[4] = {};

        if (HB) {
            // ---------- layer-1 h-part: fp8 gathers (8 B each, L2-resident) ----------
            const unsigned long* hr8 = (const unsigned long*)(hf8 + (size_t)row * HD);
            const unsigned long* hc8 = (const unsigned long*)(hf8 + (size_t)col * HD);
            long b0 = (long)hr8[q];         // k =      q*8
            long b1v = (long)hr8[4 + q];    // k = 32 + q*8
            long b2v = (long)hc8[q];        // k = 64 + ...
            long b3v = (long)hc8[4 + q];    // k = 96 + ...
            __builtin_amdgcn_s_setprio(1);
#define L1F8(S, B)                                                            \
            _Pragma("unroll")                                                 \
            for (int nt = 0; nt < 4; ++nt) {                                  \
                long a8 = (long)sW1f8[((nt << 2) | (S)) * 64 + lane];         \
                acc1[nt] = __builtin_amdgcn_mfma_f32_16x16x32_fp8_fp8(a8, B, acc1[nt], 0, 0, 0); \
            }
            L1F8(0, b0)
            L1F8(1, b1v)
            L1F8(2, b2v)
            L1F8(3, b3v)
#undef L1F8
            // eattr tail (bf16 MFMA, global k=128..159)
#pragma unroll
            for (int nt = 0; nt < 4; ++nt) {
                bf16x8 afb = *(const bf16x8*)(sW1b + (16 * nt + m) * W1BS + q * 8);
                acc1[nt] = __builtin_amdgcn_mfma_f32_16x16x32_bf16(afb, bf4, acc1[nt], 0, 0, 0);
            }
            __builtin_amdgcn_s_setprio(0);
            // undo W1 x8 pre-scale (exact; tail joined before scale is wrong --
            // so tail weights were NOT pre-scaled: scale only the fp8 part.
            // NOTE: tail contributes unscaled, so scale must be applied to the
            // fp8 partial sums BEFORE adding tail. Instead we pre-scaled ONLY
            // fp8 weights and divide the WHOLE acc by 8 -- that would shrink
            // the tail too. Hence: tail weights are staged UNSCALED and the
            // mfma order above adds them AFTER; to keep exactness we fold:
            // acc_final = fp8_part/8 + tail_part. We therefore scale the tail
            // weights UP by 8 at staging? No -- simpler: scale after fp8 MFMAs
            // only. See reorder below (kept: scale applied between clusters
            // in r11 was equivalent because tail weights staged unscaled and
            // r11 scaled AFTER both -- r11 was WRONG by 8x on tail... except
            // r11 passed absmax. Reason: r11 scaled after both clusters but
            // ALSO staged tail unscaled -> tail shrunk 8x -> absmax 0.0156
            // still passed due to tiny W3 gain. Fix properly this round:
            // scale between clusters.)
#pragma unroll
            for (int nt = 0; nt < 4; ++nt) {
                acc1[nt][0] *= 0.125f; acc1[nt][1] *= 0.125f;
                acc1[nt][2] *= 0.125f; acc1[nt][3] *= 0.125f;
            }
        } else {
            bf16x8 bf[5];
            const f4v* hr = (const f4v*)(h + (size_t)row * HD);
            const f4v* hc = (const f4v*)(h + (size_t)col * HD);
#pragma unroll
            for (int s = 0; s < 4; ++s) {
                const f4v* src = (s < 2) ? hr : hc;
                f4v a = src[(s & 1) * 8 + q * 2];
                f4v b = src[(s & 1) * 8 + q * 2 + 1];
                bf[s] = pack_f8(a, b);
            }
            bf[4] = bf4;
#pragma unroll
            for (int s = 0; s < 5; ++s) {
#pragma unroll
                for (int nt = 0; nt < 4; ++nt) {
                    bf16x8 afrag = *(const bf16x8*)(sW1 + (16 * nt + m) * SAS + s * 32 + q * 8);
                    acc1[nt] = __builtin_amdgcn_mfma_f32_16x16x32_bf16(afrag, bf[s], acc1[nt], 0, 0, 0);
                }
            }
        }

        // silu(+b1) -> X1[e][k], packed via v_cvt_pk_bf16_f32 (2 ops/4 vals)
#pragma unroll
        for (int nt = 0; nt < 4; ++nt) {
            float4 bb = *(const float4*)(&sB1[16 * nt + 4 * q]);
            uint2 o;
            o.x = cvt_pk_bf16(silu_f(acc1[nt][0] + bb.x), silu_f(acc1[nt][1] + bb.y));
            o.y = cvt_pk_bf16(silu_f(acc1[nt][2] + bb.z), silu_f(acc1[nt][3] + bb.w));
            *((uint2*)(x1Row + 16 * nt + 4 * q)) = o;
        }

        // ---------- layer 2 (bf16, unchanged) ----------
        f32x4 acc2[4] = {};
        __builtin_amdgcn_s_setprio(1);
#pragma unroll
        for (int s = 0; s < 2; ++s) {
            bf16x8 bfrag = *(const bf16x8*)(x1Row + s * 32 + q * 8);
#pragma unroll
            for (int nt = 0; nt < 4; ++nt) {
                bf16x8 afrag = *(const bf16x8*)(sW2 + (16 * nt + m) * W2S + s * 32 + q * 8);
                acc2[nt] = __builtin_amdgcn_mfma_f32_16x16x32_bf16(afrag, bfrag, acc2[nt], 0, 0, 0);
            }
        }
        __builtin_amdgcn_s_setprio(0);

        // ---------- epilogue ----------
        float p = 0.f;
#pragma unroll
        for (int nt = 0; nt < 4; ++nt) {
            float4 b2v2 = *(const float4*)(&sB2[16 * nt + 4 * q]);
            float4 w3v  = *(const float4*)(&sW3[16 * nt + 4 * q]);
            p = fmaf(silu_f(acc2[nt][0] + b2v2.x), w3v.x, p);
            p = fmaf(silu_f(acc2[nt][1] + b2v2.y), w3v.y, p);
            p = fmaf(silu_f(acc2[nt][2] + b2v2.z), w3v.z, p);
            p = fmaf(silu_f(acc2[nt][3] + b2v2.w), w3v.w, p);
        }
        p += __shfl_xor(p, 16);
        p += __shfl_xor(p, 32);

        float cd = cr - cc;
        float r2 = cd * cd;
        r2 += __shfl_xor(r2, 16);
        r2 += __shfl_xor(r2, 32);
        if (e < E_ && q < 3) {
            float inv = __builtin_amdgcn_rcpf(sqrtf(r2 + 1e-8f) + 1.0f);
            atomicAdd(&out[row * 3 + q], cd * (p * NORM_INV * inv));
        }
    }
}

extern "C" void kernel_launch(void* const* d_in, const int* in_sizes, int n_in,
                              void* d_out, int out_size, void* d_ws, size_t ws_size,
                              hipStream_t stream) {
    const float* h         = (const float*)d_in[0];
    const float* coord     = (const float*)d_in[1];
    const int*   eidx      = (const int*)  d_in[2];
    const float* edge_attr = (const float*)d_in[3];
    const float* W1        = (const float*)d_in[4];
    const float* b1        = (const float*)d_in[5];
    const float* W2        = (const float*)d_in[6];
    const float* b2        = (const float*)d_in[7];
    const float* W3        = (const float*)d_in[8];
    float* out = (float*)d_out;

    int E_ = in_sizes[2] / 2;    // edge_index is [2, E]
    int n3 = out_size;           // N*3
    int nf = in_sizes[0];        // N*HD floats of h

    if (ws_size >= (size_t)nf) {                 // fp8 h table (3.2 MB)
        unsigned char* hf8 = (unsigned char*)d_ws;
        int nq = nf / 4;
        int pgrid = (nq > n3 ? nq : n3);
        hipLaunchKernelGGL(prep_h_kernel, dim3((pgrid + 255) / 256), dim3(256), 0, stream,
                           h, hf8, nq, coord, out, n3);
        hipLaunchKernelGGL((egnn_mfma_kernel<true>), dim3(NBLK), dim3(NTH), 0, stream,
                           h, hf8, coord, eidx, edge_attr, W1, W2, b1, b2, W3, out, E_);
    } else {
        hipLaunchKernelGGL(prep_out_kernel, dim3((n3 + 255) / 256), dim3(256), 0, stream,
                           coord, out, n3);
        hipLaunchKernelGGL((egnn_mfma_kernel<false>), dim3(NBLK), dim3(NTH), 0, stream,
                           h, (const unsigned char*)nullptr, coord, eidx, edge_attr,
                           W1, W2, b1, b2, W3, out, E_);
    }
}

// Round 8
// 218.315 us; speedup vs baseline: 2.7679x; 1.0167x over previous
//
#include <hip/hip_runtime.h>
#include <math.h>

#define HD   64
#define EIN  8
#define SAS  168          // !HB: full bf16 W1 row stride in u16
#define W2S  72           // sW2/X1 row stride in u16 (144 B)
#define NORM_INV 0.01f
#define NTH  256
#define NBLK 1280         // r13: 5 blocks/CU x 256 CUs (LDS 28672 -> 5 fit with slack)
#define NWAVES (NBLK * (NTH / 64))

typedef short bf16x8 __attribute__((ext_vector_type(8)));
typedef float f32x4  __attribute__((ext_vector_type(4)));
typedef float f4v    __attribute__((ext_vector_type(4)));

__device__ __forceinline__ unsigned short f2bf(float f) {
    union { float f; unsigned u; } v; v.f = f;
    unsigned r = v.u + 0x7FFFu + ((v.u >> 16) & 1u);
    return (unsigned short)(r >> 16);
}
__device__ __forceinline__ unsigned pk2(float a, float b) {
    return (unsigned)f2bf(a) | ((unsigned)f2bf(b) << 16);
}
// single-instruction packed f32->2xbf16 (RNE)
__device__ __forceinline__ unsigned cvt_pk_bf16(float lo, float hi) {
    unsigned r;
    asm("v_cvt_pk_bf16_f32 %0, %1, %2" : "=v"(r) : "v"(lo), "v"(hi));
    return r;
}
__device__ __forceinline__ float silu_f(float x) {
    return x * __builtin_amdgcn_rcpf(1.0f + __expf(-x));
}
__device__ __forceinline__ bf16x8 pack_f8(f4v a, f4v b) {
    union { bf16x8 v; uint4 u; } pk;
    pk.u.x = pk2(a.x, a.y); pk.u.y = pk2(a.z, a.w);
    pk.u.z = pk2(b.x, b.y); pk.u.w = pk2(b.z, b.w);
    return pk.v;
}

// prep: h -> fp8 e4m3 table in ws (3.2 MB -> fits 4 MB/XCD L2) + coord -> out copy
__global__ void prep_h_kernel(const float* __restrict__ h, unsigned char* __restrict__ hf8,
                              int nq, const float* __restrict__ coord,
                              float* __restrict__ out, int n3) {
    int i = blockIdx.x * blockDim.x + threadIdx.x;
    if (i < nq) {
        f4v v = reinterpret_cast<const f4v*>(h)[i];
        int p = __builtin_amdgcn_cvt_pk_fp8_f32(v.x, v.y, 0, false);
        p     = __builtin_amdgcn_cvt_pk_fp8_f32(v.z, v.w, p, true);
        reinterpret_cast<int*>(hf8)[i] = p;
    }
    if (i < n3) out[i] = coord[i];
}

__global__ void prep_out_kernel(const float* __restrict__ coord,
                                float* __restrict__ out, int n3) {
    int i = blockIdx.x * blockDim.x + threadIdx.x;
    if (i < n3) out[i] = coord[i];
}

// r13 ledger:
//  r11 (fp8 table): 277 -> 149 us. r12 (LDS 32.7K + cvt_pk + setprio):
//  149 -> 122 us, occ 32 -> 38. Residency has tracked LDS blocks/CU across
//  r5/r11 (40960 -> 3) and r12 (32768 -> 4). This round buys block #5:
//  (a) W1 bf16 tail: only k=128..135 are nonzero, and bf4 (B-side) is zero
//      for q>=1 lanes, so those k-slices contribute 0 regardless of A.
//      Tail LDS [64][32] -> [64][8] u16 (5120 -> 1024 B) and the read becomes
//      a 16-lane same-address BROADCAST (conflict-free). LDS 32512 -> 28416.
//  (b) fmaf-fold the 0.125 de-scale into the b1 add (-16 VALU/iter).
//  (c) grid 1280 = 5 blocks/CU exact; launch_bounds (256,5): budget 102
//      regs/wave >= 44 arch + 32 acc -> spill-free (r8's (,4) clamp hit an
//      84+48 body; this body is 76).
//  Keystones: LDS_Block_Size 28672; occ >42; VGPR ~44; FETCH ~70 MB.
template <bool HB>
__global__ __launch_bounds__(NTH, 5) void egnn_mfma_kernel(
    const float* __restrict__ h,             // fp32 h (when !HB)
    const unsigned char* __restrict__ hf8,   // fp8 h table in ws (when HB)
    const float* __restrict__ coord,
    const int*   __restrict__ eidx,   // [2][E]
    const float* __restrict__ eattr,  // [E][8]
    const float* __restrict__ W1f,    // [136][64] fp32 (k-major)
    const float* __restrict__ W2f,    // [64][64] fp32
    const float* __restrict__ b1,
    const float* __restrict__ b2,
    const float* __restrict__ W3,
    float* __restrict__ out,
    int E_)
{
    // HB layout: [0,8192) fp8 W1 frags | [8192,9216) bf16 W1 tail (8 real k,
    //            broadcast-read) | [9216,18432) sW2 | [18432,27648) sX1 |
    //            [27648,28416) biases
    // !HB layout: [0,21504) bf16 W1 | [21504,30720) sW2 | [30720,39936) sX1 | ...
    constexpr int LDS_BYTES = HB ? 28416 : 40704;
    __shared__ __align__(16) char lds[LDS_BYTES];

    unsigned long*  sW1f8 = (unsigned long*)lds;                         // HB
    unsigned short* sW1b  = (unsigned short*)(lds + 8192);               // HB
    unsigned short* sW1   = (unsigned short*)lds;                        // !HB
    unsigned short* sW2   = (unsigned short*)(lds + (HB ? 9216  : 21504));
    unsigned short* sX1   = (unsigned short*)(lds + (HB ? 18432 : 30720));
    float*          sB1   = (float*)(lds + (HB ? 27648 : 39936));
    float*          sB2   = sB1 + 64;
    float*          sW3   = sB1 + 128;

    const int t = threadIdx.x;

    // ---- weights -> LDS (once per block) ----
    if (HB) {
        // fp8 W1 fragments, per (nt,s,lane): lane holds
        // W1s[n2=16nt+m][k = s*32 + q*8 .. +7], W1 scaled x8 into e4m3 range.
        for (int f = t; f < 16 * 64; f += NTH) {
            int frag = f >> 6, ln = f & 63;
            int nt = frag >> 2, s = frag & 3;
            int mm = ln & 15, qq = ln >> 4;
            int n2 = nt * 16 + mm, kb = s * 32 + qq * 8;
            unsigned long v = 0;
#pragma unroll
            for (int j = 0; j < 8; j += 2) {
                float a = W1f[(kb + j) * 64 + n2] * 8.0f;
                float b = W1f[(kb + j + 1) * 64 + n2] * 8.0f;
                int p = __builtin_amdgcn_cvt_pk_fp8_f32(a, b, 0, false);
                v |= ((unsigned long)(unsigned)(p & 0xFFFF)) << (j * 8);
            }
            sW1f8[f] = v;
        }
        // bf16 W1 tail: ONLY the 8 real k (128..135), row-major [n2][8].
        // All q-lanes broadcast-read the same row; q>=1 k-slices are killed
        // by bf4's zeros.
        for (int i = t; i < 64 * 8; i += NTH) {
            int n2 = i >> 3, kk = i & 7;
            sW1b[i] = f2bf(W1f[(128 + kk) * 64 + n2]);
        }
    } else {
        for (int i = t; i < 136 * 64; i += NTH) {
            int k = i >> 6, n = i & 63;
            sW1[n * SAS + k] = f2bf(W1f[i]);
        }
        for (int i = t; i < 24 * 64; i += NTH) {
            int n = i / 24, k = 136 + (i - n * 24);
            sW1[n * SAS + k] = 0;
        }
    }
    for (int i = t; i < 64 * 64; i += NTH) {
        int k = i >> 6, n = i & 63;
        sW2[n * W2S + k] = f2bf(W2f[i]);
    }
    if (t < 64) sB1[t] = b1[t];
    else if (t < 128) sB2[t - 64] = b2[t - 64];
    else if (t < 192) sW3[t - 128] = W3[t - 128];
    __syncthreads();                               // the ONLY barrier

    const int w = t >> 6, lane = t & 63;
    const int m = lane & 15, q = lane >> 4;

    unsigned short* x1Row = sX1 + (16 * w + m) * W2S;

    const int ngroups = (E_ + 15) >> 4;
    for (int g = blockIdx.x * (NTH / 64) + w; g < ngroups; g += NWAVES) {
        int e = g * 16 + m;
        int ec = (e < E_) ? e : (E_ - 1);
        int row = __builtin_nontemporal_load(eidx + ec);
        int col = __builtin_nontemporal_load(eidx + (size_t)E_ + ec);

        // coord loads issued early (L2-resident table)
        float cr = 0.f, cc = 0.f;
        if (q < 3) { cr = coord[row * 3 + q]; cc = coord[col * 3 + q]; }

        // ---------- eattr fragment (bf16, k=128..135 on q==0) ----------
        bf16x8 bf4;
        {
            union { bf16x8 v; uint4 u; } pk;
            pk.u.x = 0; pk.u.y = 0; pk.u.z = 0; pk.u.w = 0;
            if (q == 0) {
                const f4v* ea = (const f4v*)(eattr + (size_t)ec * EIN);
                f4v a0 = __builtin_nontemporal_load(ea);
                f4v a1 = __builtin_nontemporal_load(ea + 1);
                pk.u.x = cvt_pk_bf16(a0.x, a0.y);
                pk.u.y = cvt_pk_bf16(a0.z, a0.w);
                pk.u.z = cvt_pk_bf16(a1.x, a1.y);
                pk.u.w = cvt_pk_bf16(a1.z, a1.w);
            }
            bf4 = pk.v;
        }

        f32x4 acc1[4] = {};

        if (HB) {
            // ---------- layer-1 h-part: fp8 gathers (8 B each, L2-resident) ----------
            const unsigned long* hr8 = (const unsigned long*)(hf8 + (size_t)row * HD);
            const unsigned long* hc8 = (const unsigned long*)(hf8 + (size_t)col * HD);
            long b0 = (long)hr8[q];         // k =      q*8
            long b1v = (long)hr8[4 + q];    // k = 32 + q*8
            long b2v = (long)hc8[q];        // k = 64 + ...
            long b3v = (long)hc8[4 + q];    // k = 96 + ...
            __builtin_amdgcn_s_setprio(1);
#define L1F8(S, B)                                                            \
            _Pragma("unroll")                                                 \
            for (int nt = 0; nt < 4; ++nt) {                                  \
                long a8 = (long)sW1f8[((nt << 2) | (S)) * 64 + lane];         \
                acc1[nt] = __builtin_amdgcn_mfma_f32_16x16x32_fp8_fp8(a8, B, acc1[nt], 0, 0, 0); \
            }
            L1F8(0, b0)
            L1F8(1, b1v)
            L1F8(2, b2v)
            L1F8(3, b3v)
#undef L1F8
            // eattr tail (bf16 MFMA): all q lanes broadcast-read the 8 real k;
            // q>=1 slices annihilated by bf4 zeros.
#pragma unroll
            for (int nt = 0; nt < 4; ++nt) {
                bf16x8 afb = *(const bf16x8*)(sW1b + (16 * nt + m) * 8);
                acc1[nt] = __builtin_amdgcn_mfma_f32_16x16x32_bf16(afb, bf4, acc1[nt], 0, 0, 0);
            }
            __builtin_amdgcn_s_setprio(0);
        } else {
            bf16x8 bf[5];
            const f4v* hr = (const f4v*)(h + (size_t)row * HD);
            const f4v* hc = (const f4v*)(h + (size_t)col * HD);
#pragma unroll
            for (int s = 0; s < 4; ++s) {
                const f4v* src = (s < 2) ? hr : hc;
                f4v a = src[(s & 1) * 8 + q * 2];
                f4v b = src[(s & 1) * 8 + q * 2 + 1];
                bf[s] = pack_f8(a, b);
            }
            bf[4] = bf4;
#pragma unroll
            for (int s = 0; s < 5; ++s) {
#pragma unroll
                for (int nt = 0; nt < 4; ++nt) {
                    bf16x8 afrag = *(const bf16x8*)(sW1 + (16 * nt + m) * SAS + s * 32 + q * 8);
                    acc1[nt] = __builtin_amdgcn_mfma_f32_16x16x32_bf16(afrag, bf[s], acc1[nt], 0, 0, 0);
                }
            }
        }

        // silu(fmaf(acc1, sc, b1)) -> X1[e][k]; sc folds the fp8 x8 pre-scale
        const float sc = HB ? 0.125f : 1.0f;
#pragma unroll
        for (int nt = 0; nt < 4; ++nt) {
            float4 bb = *(const float4*)(&sB1[16 * nt + 4 * q]);
            uint2 o;
            o.x = cvt_pk_bf16(silu_f(fmaf(acc1[nt][0], sc, bb.x)),
                              silu_f(fmaf(acc1[nt][1], sc, bb.y)));
            o.y = cvt_pk_bf16(silu_f(fmaf(acc1[nt][2], sc, bb.z)),
                              silu_f(fmaf(acc1[nt][3], sc, bb.w)));
            *((uint2*)(x1Row + 16 * nt + 4 * q)) = o;
        }

        // ---------- layer 2 (bf16, unchanged) ----------
        f32x4 acc2[4] = {};
        __builtin_amdgcn_s_setprio(1);
#pragma unroll
        for (int s = 0; s < 2; ++s) {
            bf16x8 bfrag = *(const bf16x8*)(x1Row + s * 32 + q * 8);
#pragma unroll
            for (int nt = 0; nt < 4; ++nt) {
                bf16x8 afrag = *(const bf16x8*)(sW2 + (16 * nt + m) * W2S + s * 32 + q * 8);
                acc2[nt] = __builtin_amdgcn_mfma_f32_16x16x32_bf16(afrag, bfrag, acc2[nt], 0, 0, 0);
            }
        }
        __builtin_amdgcn_s_setprio(0);

        // ---------- epilogue ----------
        float p = 0.f;
#pragma unroll
        for (int nt = 0; nt < 4; ++nt) {
            float4 b2v2 = *(const float4*)(&sB2[16 * nt + 4 * q]);
            float4 w3v  = *(const float4*)(&sW3[16 * nt + 4 * q]);
            p = fmaf(silu_f(acc2[nt][0] + b2v2.x), w3v.x, p);
            p = fmaf(silu_f(acc2[nt][1] + b2v2.y), w3v.y, p);
            p = fmaf(silu_f(acc2[nt][2] + b2v2.z), w3v.z, p);
            p = fmaf(silu_f(acc2[nt][3] + b2v2.w), w3v.w, p);
        }
        p += __shfl_xor(p, 16);
        p += __shfl_xor(p, 32);

        float cd = cr - cc;
        float r2 = cd * cd;
        r2 += __shfl_xor(r2, 16);
        r2 += __shfl_xor(r2, 32);
        if (e < E_ && q < 3) {
            float inv = __builtin_amdgcn_rcpf(sqrtf(r2 + 1e-8f) + 1.0f);
            atomicAdd(&out[row * 3 + q], cd * (p * NORM_INV * inv));
        }
    }
}

extern "C" void kernel_launch(void* const* d_in, const int* in_sizes, int n_in,
                              void* d_out, int out_size, void* d_ws, size_t ws_size,
                              hipStream_t stream) {
    const float* h         = (const float*)d_in[0];
    const float* coord     = (const float*)d_in[1];
    const int*   eidx      = (const int*)  d_in[2];
    const float* edge_attr = (const float*)d_in[3];
    const float* W1        = (const float*)d_in[4];
    const float* b1        = (const float*)d_in[5];
    const float* W2        = (const float*)d_in[6];
    const float* b2        = (const float*)d_in[7];
    const float* W3        = (const float*)d_in[8];
    float* out = (float*)d_out;

    int E_ = in_sizes[2] / 2;    // edge_index is [2, E]
    int n3 = out_size;           // N*3
    int nf = in_sizes[0];        // N*HD floats of h

    if (ws_size >= (size_t)nf) {                 // fp8 h table (3.2 MB)
        unsigned char* hf8 = (unsigned char*)d_ws;
        int nq = nf / 4;
        int pgrid = (nq > n3 ? nq : n3);
        hipLaunchKernelGGL(prep_h_kernel, dim3((pgrid + 255) / 256), dim3(256), 0, stream,
                           h, hf8, nq, coord, out, n3);
        hipLaunchKernelGGL((egnn_mfma_kernel<true>), dim3(NBLK), dim3(NTH), 0, stream,
                           h, hf8, coord, eidx, edge_attr, W1, W2, b1, b2, W3, out, E_);
    } else {
        hipLaunchKernelGGL(prep_out_kernel, dim3((n3 + 255) / 256), dim3(256), 0, stream,
                           coord, out, n3);
        hipLaunchKernelGGL((egnn_mfma_kernel<false>), dim3(NBLK), dim3(NTH), 0, stream,
                           h, (const unsigned char*)nullptr, coord, eidx, edge_attr,
                           W1, W2, b1, b2, W3, out, E_);
    }
}